// Round 2
// baseline (7912.514 us; speedup 1.0000x reference)
//
#include <hip/hip_runtime.h>
#include <math.h>

#define J_ 24
#define T_ 256
#define B_ 32
#define M_ (B_*T_*J_)   // 196608 pixels

__device__ __constant__ int d_parent[24] = {-1,0,0,0,1,2,3,4,5,6,7,8,9,9,9,12,13,14,16,17,18,19,20,21};

// ---------------------------------------------------------------- adjacency
// adj_out[0..575]  = ADJ[j][k] = a(j,k)/deg(j)   (row-normalized)
// adj_out[576..599] = colsum[k] = sum_j ADJ[j][k] (for the gcn-bias reorder)
__global__ void adj_init_kernel(float* __restrict__ adj_out) {
    __shared__ float s_adj[576];
    const int i = threadIdx.x;
    if (i < 576) {
        const int j = i / 24, k = i % 24;
        float a = (j == k || d_parent[k] == j || d_parent[j] == k) ? 1.f : 0.f;
        float d = 0.f;
        for (int kk = 0; kk < 24; ++kk) {
            float av = (j == kk || d_parent[kk] == j || d_parent[j] == kk) ? 1.f : 0.f;
            d += av;
        }
        d = fmaxf(d, 1.f);
        const float v = a / d;
        s_adj[i] = v;
        adj_out[i] = v;
    }
    __syncthreads();
    if (i < 24) {
        float cs = 0.f;
        for (int j = 0; j < 24; ++j) cs += s_adj[j*24 + i];
        adj_out[576 + i] = cs;
    }
}

// ---------------------------------------------------------------- rot6d (per group)
// npix = G*T*J pixels starting at x offset; writes channels-last [pix][6]
__global__ __launch_bounds__(256) void rot6d_kernel(const float* __restrict__ x,
                                                    float* __restrict__ f0, int npix) {
    const int p = blockIdx.x * 256 + threadIdx.x;
    if (p >= npix) return;
    const float ax = x[p*3+0], ay = x[p*3+1], az = x[p*3+2];
    const float angle = sqrtf(ax*ax + ay*ay + az*az);
    const float inv = 1.f / (angle + 1e-8f);
    const float ux = ax*inv, uy = ay*inv, uz = az*inv;
    const float c = cosf(angle), s = sinf(angle), omc = 1.f - c;
    float* o = f0 + (size_t)p * 6;
    o[0] = c + omc*ux*ux;
    o[1] = omc*ux*uy - s*uz;
    o[2] = omc*uy*ux + s*uz;
    o[3] = c + omc*uy*uy;
    o[4] = omc*uz*ux - s*uy;
    o[5] = omc*uz*uy + s*ux;
}

// ---------------------------------------------------------------- repack tcn W
// tcn_w [O][C][3][1]  ->  wt [O][3][C]  (contiguous over c for vector loads)
__global__ void repack_tcn_kernel(const float* __restrict__ w, float* __restrict__ wt,
                                  int O, int C) {
    const int idx = blockIdx.x * 256 + threadIdx.x;
    if (idx >= O * 3 * C) return;
    const int o = idx / (3 * C);
    const int r = idx % (3 * C);
    const int dt = r / C, c = r % C;
    wt[idx] = w[(o * C + c) * 3 + dt];
}

// ---------------------------------------------------------------- stage A
// per (b,t): load 24 x C_IN slab, adj-mix over joints, GEMM -> 24 x C_OUT,
// fused gcn bias (col-sum corrected) + BN1 + ReLU. All pixel indices group-local.
template<int C_IN, int C_OUT>
__global__ __launch_bounds__(256) void stage_a_kernel(
    const float* __restrict__ in, const float* __restrict__ gw,
    const float* __restrict__ gb, const float* __restrict__ bn1,
    const float* __restrict__ adj, float* __restrict__ out)
{
    constexpr int O_PER = C_OUT / 64;
    constexpr int K_PER = 6;
    __shared__ float xs[J_][C_IN];
    __shared__ float xa[J_][C_IN];
    __shared__ float s_adj[608];
    const int bt = blockIdx.x;
    const int tid = threadIdx.x;

    for (int i = tid; i < 600; i += 256) s_adj[i] = adj[i];
    const float* src = in + (size_t)bt * (J_ * C_IN);
    for (int i = tid; i < J_ * C_IN; i += 256) xs[i / C_IN][i % C_IN] = src[i];
    __syncthreads();

    for (int i = tid; i < J_ * C_IN; i += 256) {
        const int k = i / C_IN, c = i % C_IN;
        float a = 0.f;
        #pragma unroll
        for (int j = 0; j < J_; ++j) a = fmaf(s_adj[j*J_ + k], xs[j][c], a);
        xa[k][c] = a;
    }
    __syncthreads();

    const int og = tid & 63;
    const int kg = tid >> 6;
    float acc[K_PER][O_PER];
    #pragma unroll
    for (int kk = 0; kk < K_PER; ++kk)
        #pragma unroll
        for (int i = 0; i < O_PER; ++i) acc[kk][i] = 0.f;

    if constexpr ((C_IN & 3) == 0) {
        for (int c = 0; c < C_IN; c += 4) {
            float4 wv[O_PER];
            #pragma unroll
            for (int i = 0; i < O_PER; ++i)
                wv[i] = *(const float4*)(gw + (size_t)(og*O_PER + i)*C_IN + c);
            #pragma unroll
            for (int kk = 0; kk < K_PER; ++kk) {
                const float4 xv = *(const float4*)(&xa[kg*K_PER + kk][c]);
                #pragma unroll
                for (int i = 0; i < O_PER; ++i) {
                    acc[kk][i] = fmaf(xv.x, wv[i].x, acc[kk][i]);
                    acc[kk][i] = fmaf(xv.y, wv[i].y, acc[kk][i]);
                    acc[kk][i] = fmaf(xv.z, wv[i].z, acc[kk][i]);
                    acc[kk][i] = fmaf(xv.w, wv[i].w, acc[kk][i]);
                }
            }
        }
    } else {
        for (int c = 0; c < C_IN; ++c) {
            float wv[O_PER];
            #pragma unroll
            for (int i = 0; i < O_PER; ++i) wv[i] = gw[(size_t)(og*O_PER + i)*C_IN + c];
            #pragma unroll
            for (int kk = 0; kk < K_PER; ++kk) {
                const float xv = xa[kg*K_PER + kk][c];
                #pragma unroll
                for (int i = 0; i < O_PER; ++i) acc[kk][i] = fmaf(xv, wv[i], acc[kk][i]);
            }
        }
    }

    float sc[O_PER], bi[O_PER], gbo[O_PER];
    #pragma unroll
    for (int i = 0; i < O_PER; ++i) {
        const int o = og*O_PER + i;
        const float s = bn1[o] / sqrtf(bn1[3*C_OUT + o] + 1e-5f);
        sc[i] = s;
        bi[i] = bn1[C_OUT + o] - bn1[2*C_OUT + o] * s;
        gbo[i] = gb[o];
    }
    #pragma unroll
    for (int kk = 0; kk < K_PER; ++kk) {
        const int k = kg*K_PER + kk;
        const float cs = s_adj[576 + k];
        float vals[O_PER];
        #pragma unroll
        for (int i = 0; i < O_PER; ++i) {
            const float v = (acc[kk][i] + gbo[i]*cs) * sc[i] + bi[i];
            vals[i] = fmaxf(v, 0.f);
        }
        float* dst = out + ((size_t)bt*J_ + k)*C_OUT + og*O_PER;
        if constexpr (O_PER == 4)
            *(float4*)dst = make_float4(vals[0], vals[1], vals[2], vals[3]);
        else
            *(float2*)dst = make_float2(vals[0], vals[1]);
    }
}

// ---------------------------------------------------------------- stage B
// temporal conv (3 taps over t) + bias + BN2 + residual + ReLU.
// RES_MODE 0: residual = res_in value (identity). RES_MODE 1: res_w @ res_in + res_b.
// POOL 1: instead of writing [bt][j][c], reduce over j and atomicAdd into
//         out[b_local*C_OUT + c] (pooled sums; caller memsets + scales later).
template<int C_IN, int C_OUT, int RES_MODE, int RES_K, int POOL>
__global__ __launch_bounds__(256) void stage_b_kernel(
    const float* __restrict__ h, const float* __restrict__ wt,
    const float* __restrict__ tb, const float* __restrict__ bn2,
    const float* __restrict__ res_in, const float* __restrict__ rw,
    const float* __restrict__ rb, float* __restrict__ out)
{
    constexpr int O_PER = C_OUT / 64;
    constexpr int K_PER = 6;
    constexpr int CT = (C_IN < 128) ? C_IN : 128;   // C_in tile (LDS budget)
    __shared__ float hs[3*J_][CT];
    const int bt = blockIdx.x;
    const int b = bt >> 8;           // group-local batch
    const int t = bt & (T_ - 1);
    const int tid = threadIdx.x;
    const int og = tid & 63;
    const int kg = tid >> 6;

    float acc[K_PER][O_PER];
    #pragma unroll
    for (int kk = 0; kk < K_PER; ++kk)
        #pragma unroll
        for (int i = 0; i < O_PER; ++i) acc[kk][i] = 0.f;

    for (int ci0 = 0; ci0 < C_IN; ci0 += CT) {
        if (ci0 != 0) __syncthreads();
        for (int i = tid*4; i < 3*J_*CT; i += 1024) {
            const int row = i / CT;
            const int col = i - row*CT;
            const int dt = row / J_;
            const int ts = t + dt - 1;
            float4 v = make_float4(0.f, 0.f, 0.f, 0.f);
            if ((unsigned)ts < (unsigned)T_) {
                const size_t srcOff = (((size_t)b*T_ + ts)*J_ + (row - dt*J_)) * C_IN + ci0 + col;
                v = *(const float4*)(h + srcOff);
            }
            *(float4*)(&hs[row][col]) = v;
        }
        __syncthreads();
        #pragma unroll
        for (int dt = 0; dt < 3; ++dt) {
            for (int c = 0; c < CT; c += 4) {
                float4 wv[O_PER];
                #pragma unroll
                for (int i = 0; i < O_PER; ++i)
                    wv[i] = *(const float4*)(wt + ((size_t)(og*O_PER + i)*3 + dt)*C_IN + ci0 + c);
                #pragma unroll
                for (int kk = 0; kk < K_PER; ++kk) {
                    const float4 xv = *(const float4*)(&hs[dt*J_ + kg*K_PER + kk][c]);
                    #pragma unroll
                    for (int i = 0; i < O_PER; ++i) {
                        acc[kk][i] = fmaf(xv.x, wv[i].x, acc[kk][i]);
                        acc[kk][i] = fmaf(xv.y, wv[i].y, acc[kk][i]);
                        acc[kk][i] = fmaf(xv.z, wv[i].z, acc[kk][i]);
                        acc[kk][i] = fmaf(xv.w, wv[i].w, acc[kk][i]);
                    }
                }
            }
        }
    }

    // residual
    float r[K_PER][O_PER];
    if constexpr (RES_MODE == 0) {
        #pragma unroll
        for (int kk = 0; kk < K_PER; ++kk) {
            const size_t row = (size_t)bt*J_ + kg*K_PER + kk;
            if constexpr (O_PER == 4) {
                const float4 v = *(const float4*)(res_in + row*C_OUT + og*4);
                r[kk][0] = v.x; r[kk][1] = v.y; r[kk][2] = v.z; r[kk][3] = v.w;
            } else {
                const float2 v = *(const float2*)(res_in + row*C_OUT + og*2);
                r[kk][0] = v.x; r[kk][1] = v.y;
            }
        }
    } else {
        #pragma unroll
        for (int kk = 0; kk < K_PER; ++kk)
            #pragma unroll
            for (int i = 0; i < O_PER; ++i) r[kk][i] = 0.f;
        if constexpr ((RES_K & 3) == 0) {
            for (int c = 0; c < RES_K; c += 4) {
                float4 wv[O_PER];
                #pragma unroll
                for (int i = 0; i < O_PER; ++i)
                    wv[i] = *(const float4*)(rw + (size_t)(og*O_PER + i)*RES_K + c);
                #pragma unroll
                for (int kk = 0; kk < K_PER; ++kk) {
                    const size_t row = (size_t)bt*J_ + kg*K_PER + kk;
                    const float4 xv = *(const float4*)(res_in + row*RES_K + c);
                    #pragma unroll
                    for (int i = 0; i < O_PER; ++i) {
                        r[kk][i] = fmaf(xv.x, wv[i].x, r[kk][i]);
                        r[kk][i] = fmaf(xv.y, wv[i].y, r[kk][i]);
                        r[kk][i] = fmaf(xv.z, wv[i].z, r[kk][i]);
                        r[kk][i] = fmaf(xv.w, wv[i].w, r[kk][i]);
                    }
                }
            }
        } else {
            for (int c = 0; c < RES_K; ++c) {
                float wv[O_PER];
                #pragma unroll
                for (int i = 0; i < O_PER; ++i) wv[i] = rw[(size_t)(og*O_PER + i)*RES_K + c];
                #pragma unroll
                for (int kk = 0; kk < K_PER; ++kk) {
                    const size_t row = (size_t)bt*J_ + kg*K_PER + kk;
                    const float xv = res_in[row*RES_K + c];
                    #pragma unroll
                    for (int i = 0; i < O_PER; ++i) r[kk][i] = fmaf(xv, wv[i], r[kk][i]);
                }
            }
        }
    }

    float sc[O_PER], bi[O_PER], tbo[O_PER], rbo[O_PER];
    #pragma unroll
    for (int i = 0; i < O_PER; ++i) {
        const int o = og*O_PER + i;
        const float s = bn2[o] / sqrtf(bn2[3*C_OUT + o] + 1e-5f);
        sc[i] = s;
        bi[i] = bn2[C_OUT + o] - bn2[2*C_OUT + o] * s;
        tbo[i] = tb[o];
        rbo[i] = (RES_MODE == 1) ? rb[o] : 0.f;
    }

    if constexpr (POOL) {
        __shared__ float red[4][C_OUT];
        float psum[O_PER];
        #pragma unroll
        for (int i = 0; i < O_PER; ++i) psum[i] = 0.f;
        #pragma unroll
        for (int kk = 0; kk < K_PER; ++kk) {
            #pragma unroll
            for (int i = 0; i < O_PER; ++i) {
                const float z = (acc[kk][i] + tbo[i]) * sc[i] + bi[i] + r[kk][i] + rbo[i];
                psum[i] += fmaxf(z, 0.f);
            }
        }
        #pragma unroll
        for (int i = 0; i < O_PER; ++i) red[kg][og*O_PER + i] = psum[i];
        __syncthreads();
        if (tid < C_OUT) {
            const float s = red[0][tid] + red[1][tid] + red[2][tid] + red[3][tid];
            atomicAdd(out + (size_t)b*C_OUT + tid, s);
        }
    } else {
        #pragma unroll
        for (int kk = 0; kk < K_PER; ++kk) {
            const int k = kg*K_PER + kk;
            const size_t row = (size_t)bt*J_ + k;
            float vals[O_PER];
            #pragma unroll
            for (int i = 0; i < O_PER; ++i) {
                const float z = (acc[kk][i] + tbo[i]) * sc[i] + bi[i] + r[kk][i] + rbo[i];
                vals[i] = fmaxf(z, 0.f);
            }
            float* dst = out + row*C_OUT + og*O_PER;
            if constexpr (O_PER == 4)
                *(float4*)dst = make_float4(vals[0], vals[1], vals[2], vals[3]);
            else
                *(float2*)dst = make_float2(vals[0], vals[1]);
        }
    }
}

// ---------------------------------------------------------------- head
__global__ __launch_bounds__(256) void head_kernel(const float* __restrict__ pooled_sums,
    const float* __restrict__ ow, const float* __restrict__ ob, float* __restrict__ outp) {
    __shared__ float pooled[256];
    const int b = blockIdx.x, tid = threadIdx.x;
    pooled[tid] = pooled_sums[(size_t)b*256 + tid] * (1.f/6144.f);
    __syncthreads();
    for (int rep = 0; rep < 2; ++rep) {
        const int oo = rep*256 + tid;
        float a = ob[oo];
        const float4* wr = (const float4*)(ow + (size_t)oo*256);
        for (int c4 = 0; c4 < 64; ++c4) {
            const float4 w = wr[c4];
            const float4 p = *(const float4*)&pooled[c4*4];
            a += w.x*p.x + w.y*p.y + w.z*p.z + w.w*p.w;
        }
        outp[(size_t)b*512 + oo] = a;
    }
}

// ---------------------------------------------------------------- launch
extern "C" void kernel_launch(void* const* d_in, const int* in_sizes, int n_in,
                              void* d_out, int out_size, void* d_ws, size_t ws_size,
                              hipStream_t stream)
{
    const float* x        = (const float*)d_in[0];
    const float* b1_gcn_w = (const float*)d_in[1];
    const float* b1_gcn_b = (const float*)d_in[2];
    const float* b1_bn1   = (const float*)d_in[3];
    const float* b1_tcn_w = (const float*)d_in[4];
    const float* b1_tcn_b = (const float*)d_in[5];
    const float* b1_bn2   = (const float*)d_in[6];
    const float* b1_res_w = (const float*)d_in[7];
    const float* b1_res_b = (const float*)d_in[8];
    const float* b2_gcn_w = (const float*)d_in[9];
    const float* b2_gcn_b = (const float*)d_in[10];
    const float* b2_bn1   = (const float*)d_in[11];
    const float* b2_tcn_w = (const float*)d_in[12];
    const float* b2_tcn_b = (const float*)d_in[13];
    const float* b2_bn2   = (const float*)d_in[14];
    const float* b3_gcn_w = (const float*)d_in[15];
    const float* b3_gcn_b = (const float*)d_in[16];
    const float* b3_bn1   = (const float*)d_in[17];
    const float* b3_tcn_w = (const float*)d_in[18];
    const float* b3_tcn_b = (const float*)d_in[19];
    const float* b3_bn2   = (const float*)d_in[20];
    const float* b3_res_w = (const float*)d_in[21];
    const float* b3_res_b = (const float*)d_in[22];
    const float* out_w    = (const float*)d_in[23];
    const float* out_b    = (const float*)d_in[24];

    // ---- adaptive batch-group size: largest G whose workspace fits ws_size
    const size_t fixed_f = 640 + 2*49152 + 196608 + 8192;   // adj + wt1/wt2 + wt3 + pooled
    // per-group floats: f0 (MG*6) + BufH (MG*256) + BufF1 (MG*128) + BufF2 (MG*128)
    int G = 1;
    {
        const int tiers[6] = {32, 16, 8, 4, 2, 1};
        for (int ti = 0; ti < 6; ++ti) {
            const size_t need = (fixed_f + (size_t)tiers[ti]*6144*(6 + 256 + 128 + 128)) * 4;
            if (need <= ws_size) { G = tiers[ti]; break; }
        }
    }
    const size_t MG = (size_t)G * 6144;   // group pixels

    float* ws     = (float*)d_ws;
    float* adjp   = ws;                       // 640
    float* wt1    = adjp + 640;               // 128*3*128
    float* wt2    = wt1 + 49152;              // 128*3*128
    float* wt3    = wt2 + 49152;              // 256*3*256
    float* pooled = wt3 + 196608;             // 32*256 pooled sums
    float* f0g    = pooled + 8192;            // MG*6
    float* bufH   = f0g + MG*6;               // MG*256 (h1/h2 in first half, h3 full)
    float* bufF1  = bufH + MG*256;            // MG*128 (f1)
    float* bufF2  = bufF1 + MG*128;           // MG*128 (f2)

    hipMemsetAsync(pooled, 0, 8192*sizeof(float), stream);
    adj_init_kernel<<<1, 576, 0, stream>>>(adjp);
    repack_tcn_kernel<<<(128*3*128 + 255)/256, 256, 0, stream>>>(b1_tcn_w, wt1, 128, 128);
    repack_tcn_kernel<<<(128*3*128 + 255)/256, 256, 0, stream>>>(b2_tcn_w, wt2, 128, 128);
    repack_tcn_kernel<<<(256*3*256 + 255)/256, 256, 0, stream>>>(b3_tcn_w, wt3, 256, 256);

    for (int b0 = 0; b0 < B_; b0 += G) {
        const int grid = G * T_;                       // one block per (b,t)
        const int npix = G * 6144;
        rot6d_kernel<<<(npix + 255)/256, 256, 0, stream>>>(x + (size_t)b0*6144*3, f0g, npix);

        stage_a_kernel<6, 128><<<grid, 256, 0, stream>>>(
            f0g, b1_gcn_w, b1_gcn_b, b1_bn1, adjp, bufH);
        stage_b_kernel<128, 128, 1, 6, 0><<<grid, 256, 0, stream>>>(
            bufH, wt1, b1_tcn_b, b1_bn2, f0g, b1_res_w, b1_res_b, bufF1);
        stage_a_kernel<128, 128><<<grid, 256, 0, stream>>>(
            bufF1, b2_gcn_w, b2_gcn_b, b2_bn1, adjp, bufH);
        stage_b_kernel<128, 128, 0, 0, 0><<<grid, 256, 0, stream>>>(
            bufH, wt2, b2_tcn_b, b2_bn2, bufF1, nullptr, nullptr, bufF2);
        stage_a_kernel<128, 256><<<grid, 256, 0, stream>>>(
            bufF2, b3_gcn_w, b3_gcn_b, b3_bn1, adjp, bufH);
        stage_b_kernel<256, 256, 1, 128, 1><<<grid, 256, 0, stream>>>(
            bufH, wt3, b3_tcn_b, b3_bn2, bufF2, b3_res_w, b3_res_b, pooled + (size_t)b0*256);
    }

    head_kernel<<<B_, 256, 0, stream>>>(pooled, out_w, out_b, (float*)d_out);
}

// Round 3
// 738.688 us; speedup vs baseline: 10.7116x; 10.7116x over previous
//
#include <hip/hip_runtime.h>
#include <math.h>

#define J_ 24
#define T_ 256
#define B_ 32

typedef short short8v __attribute__((ext_vector_type(8)));   // 8 x bf16 (4 VGPR)
typedef float f32x4  __attribute__((ext_vector_type(4)));    // MFMA acc

__device__ __forceinline__ short f2bf(float f) {
    unsigned u = __float_as_uint(f);
    u += 0x7fffu + ((u >> 16) & 1u);          // round-to-nearest-even
    return (short)(u >> 16);
}
__device__ __forceinline__ float bf2f(short s) {
    return __uint_as_float(((unsigned)(unsigned short)s) << 16);
}

__device__ __constant__ int d_parent[24] = {-1,0,0,0,1,2,3,4,5,6,7,8,9,9,9,12,13,14,16,17,18,19,20,21};

// ---------------------------------------------------------------- adjacency
// adj[0..575] = ADJ[j][k] (row-normalized), adj[576..599] = column sums
__global__ void adj_init_kernel(float* __restrict__ adj_out) {
    __shared__ float s_adj[576];
    const int i = threadIdx.x;
    if (i < 576) {
        const int j = i / 24, k = i % 24;
        float a = (j == k || d_parent[k] == j || d_parent[j] == k) ? 1.f : 0.f;
        float d = 0.f;
        for (int kk = 0; kk < 24; ++kk)
            d += (j == kk || d_parent[kk] == j || d_parent[j] == kk) ? 1.f : 0.f;
        d = fmaxf(d, 1.f);
        const float v = a / d;
        s_adj[i] = v;
        adj_out[i] = v;
    }
    __syncthreads();
    if (i < 24) {
        float cs = 0.f;
        for (int j = 0; j < 24; ++j) cs += s_adj[j*24 + i];
        adj_out[576 + i] = cs;
    }
}

// ---------------------------------------------------------------- weight prep (bf16 + BN fold)
// gcn weights: out[o][c] = s(o) * w[o][c], s = gamma/sqrt(var+eps) from bn (stacked [4][N])
__global__ void fold_gw_kernel(const float* __restrict__ w, const float* __restrict__ bn,
                               short* __restrict__ outp, int N, int C) {
    const int i = blockIdx.x * 256 + threadIdx.x;
    if (i >= N * C) return;
    const int o = i / C;
    const float s = bn[o] * rsqrtf(bn[3*N + o] + 1e-5f);
    outp[i] = f2bf(s * w[i]);
}
// tcn weights [O][C][3][1] -> [O][dt*C+c] scaled by bn2 s
__global__ void fold_wt_kernel(const float* __restrict__ w, const float* __restrict__ bn,
                               short* __restrict__ outp, int N, int C) {
    const int i = blockIdx.x * 256 + threadIdx.x;
    if (i >= N * 3 * C) return;
    const int o = i / (3 * C);
    const int r = i % (3 * C);
    const int dt = r / C, c = r % C;
    const float s = bn[o] * rsqrtf(bn[3*N + o] + 1e-5f);
    outp[i] = f2bf(s * w[(o * C + c) * 3 + dt]);
}
// plain fp32 -> bf16 convert (residual weights)
__global__ void conv_w_kernel(const float* __restrict__ w, short* __restrict__ outp, int n) {
    const int i = blockIdx.x * 256 + threadIdx.x;
    if (i < n) outp[i] = f2bf(w[i]);
}

// ---------------------------------------------------------------- front: rot6d + block1 stage_a + R1
// per (b,t) slab: rot6d (fp32), adjmix on 6ch, h1 = relu(fold_bn1(adjmix(W1 x)) + bias), R1 = rw1 x + rb1
__global__ __launch_bounds__(256) void front_kernel(
    const float* __restrict__ x, const float* __restrict__ gw1, const float* __restrict__ gb1,
    const float* __restrict__ bn1, const float* __restrict__ rw1, const float* __restrict__ rb1,
    const float* __restrict__ adjp, short* __restrict__ h1, short* __restrict__ R1)
{
    __shared__ float x6[24][6];
    __shared__ float xa[24][6];
    __shared__ float sgw[768];
    __shared__ float srw[768];
    __shared__ float sadj[600];
    const int slab = blockIdx.x;
    const int tid = threadIdx.x;

    for (int i = tid; i < 600; i += 256) sadj[i] = adjp[i];
    for (int i = tid; i < 768; i += 256) { sgw[i] = gw1[i]; srw[i] = rw1[i]; }
    if (tid < 24) {
        const float* xp = x + ((size_t)slab * 24 + tid) * 3;
        const float ax = xp[0], ay = xp[1], az = xp[2];
        const float angle = sqrtf(ax*ax + ay*ay + az*az);
        const float inv = 1.f / (angle + 1e-8f);
        const float ux = ax*inv, uy = ay*inv, uz = az*inv;
        const float c = cosf(angle), s = sinf(angle), omc = 1.f - c;
        x6[tid][0] = c + omc*ux*ux;
        x6[tid][1] = omc*ux*uy - s*uz;
        x6[tid][2] = omc*uy*ux + s*uz;
        x6[tid][3] = c + omc*uy*uy;
        x6[tid][4] = omc*uz*ux - s*uy;
        x6[tid][5] = omc*uz*uy + s*ux;
    }
    __syncthreads();
    if (tid < 144) {
        const int k = tid / 6, c = tid % 6;
        float a = 0.f;
        #pragma unroll
        for (int j = 0; j < 24; ++j) a = fmaf(sadj[j*24 + k], x6[j][c], a);
        xa[k][c] = a;
    }
    __syncthreads();
    for (int idx = tid; idx < 24*128; idx += 256) {
        const int k = idx >> 7, o = idx & 127;
        float acc = 0.f, r = 0.f;
        #pragma unroll
        for (int c = 0; c < 6; ++c) {
            acc = fmaf(xa[k][c], sgw[o*6 + c], acc);
            r   = fmaf(x6[k][c], srw[o*6 + c], r);
        }
        const float s = bn1[o] * rsqrtf(bn1[384 + o] + 1e-5f);
        const float t = bn1[128 + o] - bn1[256 + o] * s;
        const float val = s * acc + t + s * gb1[o] * sadj[576 + k];
        const size_t row = (size_t)slab * 24 + k;
        h1[row * 128 + o] = f2bf(fmaxf(val, 0.f));
        R1[row * 128 + o] = f2bf(r + rb1[o]);
    }
}

// ---------------------------------------------------------------- premix (adjacency on bf16 activations)
template<int C>
__global__ __launch_bounds__(256) void premix_kernel(const short* __restrict__ in,
                                                     const float* __restrict__ adjp,
                                                     short* __restrict__ outp) {
    __shared__ float xs[24][C];
    __shared__ float sadj[576];
    const int slab = blockIdx.x, tid = threadIdx.x;
    for (int i = tid; i < 576; i += 256) sadj[i] = adjp[i];
    const short* src = in + (size_t)slab * 24 * C;
    for (int i = tid; i < 24*C; i += 256) xs[i / C][i % C] = bf2f(src[i]);
    __syncthreads();
    short* dst = outp + (size_t)slab * 24 * C;
    for (int i = tid; i < 24*C; i += 256) {
        const int k = i / C, c = i % C;
        float a = 0.f;
        #pragma unroll
        for (int j = 0; j < 24; ++j) a = fmaf(sadj[j*24 + k], xs[j][c], a);
        dst[i] = f2bf(a);
    }
}

// ---------------------------------------------------------------- plain GEMM (K=128), MFMA
// out[M,N] = A[M,128] @ Bw[N,128]^T ; BIAS_ADJ: + t[o] + s[o]*gb[o]*colsum[row%24], relu
//                                     else:    + rb[o], no relu
template<int N_COUT, int BIAS_ADJ, int RELU>
__global__ __launch_bounds__(256) void gemm_plain_kernel(
    const short* __restrict__ A, const short* __restrict__ Bw,
    const float* __restrict__ bn, const float* __restrict__ gb,
    const float* __restrict__ adjp, const float* __restrict__ rb,
    short* __restrict__ outp)
{
    __shared__ short lds[128 * 128];
    const int r0 = blockIdx.x * 128, n0 = blockIdx.y * 128;
    const int tid = threadIdx.x, l = tid & 63, wid = tid >> 6;
    const int m0w = (wid >> 1) * 64, n0w = (wid & 1) * 64;
    const int lr = l & 15, lk = l >> 4;

    for (int ch = tid; ch < 2048; ch += 256) {
        const int row = ch >> 4, c16 = ch & 15;
        const float4 v = *(const float4*)(A + (size_t)(r0 + row) * 128 + c16 * 8);
        *(float4*)((char*)lds + row * 256 + ((c16 * 16) ^ ((row & 7) << 4))) = v;
    }
    __syncthreads();

    f32x4 acc[4][4];
    #pragma unroll
    for (int mi = 0; mi < 4; ++mi)
        #pragma unroll
        for (int ni = 0; ni < 4; ++ni) acc[mi][ni] = (f32x4){0.f, 0.f, 0.f, 0.f};

    #pragma unroll
    for (int kc = 0; kc < 4; ++kc) {
        short8v bfr[4], afr[4];
        #pragma unroll
        for (int ni = 0; ni < 4; ++ni) {
            const int n = n0 + n0w + ni * 16 + lr;
            bfr[ni] = *(const short8v*)(Bw + (size_t)n * 128 + kc * 32 + lk * 8);
        }
        #pragma unroll
        for (int mi = 0; mi < 4; ++mi) {
            const int row = m0w + mi * 16 + lr;
            afr[mi] = *(const short8v*)((char*)lds + row * 256 + ((kc * 64 + lk * 16) ^ ((row & 7) << 4)));
        }
        #pragma unroll
        for (int mi = 0; mi < 4; ++mi)
            #pragma unroll
            for (int ni = 0; ni < 4; ++ni)
                acc[mi][ni] = __builtin_amdgcn_mfma_f32_16x16x32_bf16(afr[mi], bfr[ni], acc[mi][ni], 0, 0, 0);
    }

    #pragma unroll
    for (int ni = 0; ni < 4; ++ni) {
        const int o = n0 + n0w + ni * 16 + lr;
        float t = 0.f, gbs = 0.f, biasc = 0.f;
        if (BIAS_ADJ) {
            const float s = bn[o] * rsqrtf(bn[3*N_COUT + o] + 1e-5f);
            t = bn[N_COUT + o] - bn[2*N_COUT + o] * s;
            gbs = s * gb[o];
        } else {
            biasc = rb[o];
        }
        #pragma unroll
        for (int mi = 0; mi < 4; ++mi)
            #pragma unroll
            for (int rg = 0; rg < 4; ++rg) {
                const int rl = m0w + mi * 16 + lk * 4 + rg;
                float v = acc[mi][ni][rg];
                if (BIAS_ADJ) v += t + gbs * adjp[576 + (r0 + rl) % 24];
                else v += biasc;
                if (RELU) v = fmaxf(v, 0.f);
                outp[(size_t)(r0 + rl) * N_COUT + o] = f2bf(v);
            }
    }
}

// ---------------------------------------------------------------- conv GEMM (temporal 3-tap), MFMA
// out = relu( conv3(A) @ Bw + (s*tb+t) + Res )  ; POOL: reduce rows, atomicAdd pooled[b*256+col]
template<int C_IN, int N_COUT, int POOL>
__global__ __launch_bounds__(256) void gemm_conv_kernel(
    const short* __restrict__ A, const short* __restrict__ Bw,
    const float* __restrict__ bn, const float* __restrict__ tb,
    const short* __restrict__ Res, short* __restrict__ outp,
    float* __restrict__ pooled)
{
    __shared__ short lds[176 * 128];
    const int r0 = blockIdx.x * 128, n0 = blockIdx.y * 128;
    const int bb = r0 / 6144;                     // batch within group (6144 % 128 == 0)
    const int bstart = bb * 6144, bend = bstart + 6144;
    const int tid = threadIdx.x, l = tid & 63, wid = tid >> 6;
    const int m0w = (wid >> 1) * 64, n0w = (wid & 1) * 64;
    const int lr = l & 15, lk = l >> 4;

    f32x4 acc[4][4];
    #pragma unroll
    for (int mi = 0; mi < 4; ++mi)
        #pragma unroll
        for (int ni = 0; ni < 4; ++ni) acc[mi][ni] = (f32x4){0.f, 0.f, 0.f, 0.f};

    constexpr int NP = C_IN / 128;
    for (int p = 0; p < NP; ++p) {
        if (p) __syncthreads();
        for (int ch = tid; ch < 176 * 16; ch += 256) {
            const int row = ch >> 4, c16 = ch & 15;
            const int gr = r0 - 24 + row;
            float4 v = make_float4(0.f, 0.f, 0.f, 0.f);
            if (gr >= bstart && gr < bend)
                v = *(const float4*)(A + (size_t)gr * C_IN + p * 128 + c16 * 8);
            *(float4*)((char*)lds + row * 256 + ((c16 * 16) ^ ((row & 7) << 4))) = v;
        }
        __syncthreads();
        #pragma unroll
        for (int dt = 0; dt < 3; ++dt) {
            #pragma unroll
            for (int kc = 0; kc < 4; ++kc) {
                short8v bfr[4], afr[4];
                #pragma unroll
                for (int ni = 0; ni < 4; ++ni) {
                    const int n = n0 + n0w + ni * 16 + lr;
                    bfr[ni] = *(const short8v*)(Bw + (size_t)n * (3 * C_IN) + dt * C_IN + p * 128 + kc * 32 + lk * 8);
                }
                #pragma unroll
                for (int mi = 0; mi < 4; ++mi) {
                    const int row = m0w + dt * 24 + mi * 16 + lr;   // lds row = out_row + dt*24
                    afr[mi] = *(const short8v*)((char*)lds + row * 256 + ((kc * 64 + lk * 16) ^ ((row & 7) << 4)));
                }
                #pragma unroll
                for (int mi = 0; mi < 4; ++mi)
                    #pragma unroll
                    for (int ni = 0; ni < 4; ++ni)
                        acc[mi][ni] = __builtin_amdgcn_mfma_f32_16x16x32_bf16(afr[mi], bfr[ni], acc[mi][ni], 0, 0, 0);
            }
        }
    }

    float psum[4] = {0.f, 0.f, 0.f, 0.f};
    #pragma unroll
    for (int ni = 0; ni < 4; ++ni) {
        const int o = n0 + n0w + ni * 16 + lr;
        const float s = bn[o] * rsqrtf(bn[3*N_COUT + o] + 1e-5f);
        const float t = bn[N_COUT + o] - bn[2*N_COUT + o] * s;
        const float bias = s * tb[o] + t;
        #pragma unroll
        for (int mi = 0; mi < 4; ++mi)
            #pragma unroll
            for (int rg = 0; rg < 4; ++rg) {
                const int rl = m0w + mi * 16 + lk * 4 + rg;
                float v = acc[mi][ni][rg] + bias;
                v += bf2f(Res[(size_t)(r0 + rl) * N_COUT + o]);
                v = fmaxf(v, 0.f);
                if (POOL) psum[ni] += v;
                else outp[(size_t)(r0 + rl) * N_COUT + o] = f2bf(v);
            }
    }
    if (POOL) {
        #pragma unroll
        for (int ni = 0; ni < 4; ++ni) {
            float v = psum[ni];
            v += __shfl_xor(v, 16);
            v += __shfl_xor(v, 32);
            if (l < 16) atomicAdd(pooled + (size_t)bb * 256 + (n0 + n0w + ni * 16 + l), v);
        }
    }
}

// ---------------------------------------------------------------- head
__global__ __launch_bounds__(256) void head_kernel(const float* __restrict__ pooled_sums,
    const float* __restrict__ ow, const float* __restrict__ ob, float* __restrict__ outp) {
    __shared__ float pooled[256];
    const int b = blockIdx.x, tid = threadIdx.x;
    pooled[tid] = pooled_sums[(size_t)b*256 + tid] * (1.f/6144.f);
    __syncthreads();
    for (int rep = 0; rep < 2; ++rep) {
        const int oo = rep*256 + tid;
        float a = ob[oo];
        const float4* wr = (const float4*)(ow + (size_t)oo*256);
        for (int c4 = 0; c4 < 64; ++c4) {
            const float4 w = wr[c4];
            const float4 p = *(const float4*)&pooled[c4*4];
            a += w.x*p.x + w.y*p.y + w.z*p.z + w.w*p.w;
        }
        outp[(size_t)b*512 + oo] = a;
    }
}

// ---------------------------------------------------------------- launch
extern "C" void kernel_launch(void* const* d_in, const int* in_sizes, int n_in,
                              void* d_out, int out_size, void* d_ws, size_t ws_size,
                              hipStream_t stream)
{
    const float* x        = (const float*)d_in[0];
    const float* b1_gcn_w = (const float*)d_in[1];
    const float* b1_gcn_b = (const float*)d_in[2];
    const float* b1_bn1   = (const float*)d_in[3];
    const float* b1_tcn_w = (const float*)d_in[4];
    const float* b1_tcn_b = (const float*)d_in[5];
    const float* b1_bn2   = (const float*)d_in[6];
    const float* b1_res_w = (const float*)d_in[7];
    const float* b1_res_b = (const float*)d_in[8];
    const float* b2_gcn_w = (const float*)d_in[9];
    const float* b2_gcn_b = (const float*)d_in[10];
    const float* b2_bn1   = (const float*)d_in[11];
    const float* b2_tcn_w = (const float*)d_in[12];
    const float* b2_tcn_b = (const float*)d_in[13];
    const float* b2_bn2   = (const float*)d_in[14];
    const float* b3_gcn_w = (const float*)d_in[15];
    const float* b3_gcn_b = (const float*)d_in[16];
    const float* b3_bn1   = (const float*)d_in[17];
    const float* b3_tcn_w = (const float*)d_in[18];
    const float* b3_tcn_b = (const float*)d_in[19];
    const float* b3_bn2   = (const float*)d_in[20];
    const float* b3_res_w = (const float*)d_in[21];
    const float* b3_res_b = (const float*)d_in[22];
    const float* out_w    = (const float*)d_in[23];
    const float* out_b    = (const float*)d_in[24];

    // ---- workspace carve (fixed part)
    char* w = (char*)d_ws;
    float* adjp = (float*)w;  w += 2560;                 // 600 used, pad
    short* wt1b = (short*)w;  w += 128*384*2;
    short* wt2b = (short*)w;  w += 128*384*2;
    short* wt3b = (short*)w;  w += 256*768*2;
    short* gw2b = (short*)w;  w += 128*128*2;
    short* gw3b = (short*)w;  w += 256*128*2;
    short* rw3b = (short*)w;  w += 256*128*2;
    float* pooled = (float*)w; w += 32*256*4;
    const size_t fixed = (size_t)(w - (char*)d_ws);

    // ---- adaptive batch-group: per-G bytes = 6144*(3*128*2 + 2*256*2) = 11,010,048
    int G = 1;
    {
        const int tiers[6] = {32, 16, 8, 4, 2, 1};
        for (int ti = 0; ti < 6; ++ti) {
            const size_t need = fixed + (size_t)tiers[ti] * 11010048ull;
            if (need <= ws_size) { G = tiers[ti]; break; }
        }
    }
    const size_t MG = (size_t)G * 6144;

    short* slotA = (short*)w;            // MG*128
    short* slotB = slotA + MG*128;       // MG*128
    short* slotC = slotB + MG*128;       // MG*128
    short* slotE = slotC + MG*128;       // MG*256
    short* slotF = slotE + MG*256;       // MG*256

    hipMemsetAsync(pooled, 0, 32*256*sizeof(float), stream);
    adj_init_kernel<<<1, 576, 0, stream>>>(adjp);
    fold_wt_kernel<<<(128*384 + 255)/256, 256, 0, stream>>>(b1_tcn_w, b1_bn2, wt1b, 128, 128);
    fold_wt_kernel<<<(128*384 + 255)/256, 256, 0, stream>>>(b2_tcn_w, b2_bn2, wt2b, 128, 128);
    fold_wt_kernel<<<(256*768 + 255)/256, 256, 0, stream>>>(b3_tcn_w, b3_bn2, wt3b, 256, 256);
    fold_gw_kernel<<<(128*128 + 255)/256, 256, 0, stream>>>(b2_gcn_w, b2_bn1, gw2b, 128, 128);
    fold_gw_kernel<<<(256*128 + 255)/256, 256, 0, stream>>>(b3_gcn_w, b3_bn1, gw3b, 256, 128);
    conv_w_kernel<<<(256*128 + 255)/256, 256, 0, stream>>>(b3_res_w, rw3b, 256*128);

    for (int b0 = 0; b0 < B_; b0 += G) {
        const int mt = 48 * G;                       // MG/128
        const float* xg = x + (size_t)b0 * 6144 * 3;

        // block 1: front (h1=A, R1=B) -> conv b1 (f1=C)
        front_kernel<<<G*256, 256, 0, stream>>>(xg, b1_gcn_w, b1_gcn_b, b1_bn1,
                                                b1_res_w, b1_res_b, adjp, slotA, slotB);
        gemm_conv_kernel<128, 128, 0><<<dim3(mt, 1), 256, 0, stream>>>(
            slotA, wt1b, b1_bn2, b1_tcn_b, slotB, slotC, nullptr);

        // block 2: premix f1 -> A ; stage_a2 -> h2=B ; conv b2 (res=f1=C) -> f2=A
        premix_kernel<128><<<G*256, 256, 0, stream>>>(slotC, adjp, slotA);
        gemm_plain_kernel<128, 1, 1><<<dim3(mt, 1), 256, 0, stream>>>(
            slotA, gw2b, b2_bn1, b2_gcn_b, adjp, nullptr, slotB);
        gemm_conv_kernel<128, 128, 0><<<dim3(mt, 1), 256, 0, stream>>>(
            slotB, wt2b, b2_bn2, b2_tcn_b, slotC, slotA, nullptr);

        // block 3: premix f2 -> B ; stage_a3 -> h3=E ; R3 (from f2=A) -> F ; conv b3 + pool
        premix_kernel<128><<<G*256, 256, 0, stream>>>(slotA, adjp, slotB);
        gemm_plain_kernel<256, 1, 1><<<dim3(mt, 2), 256, 0, stream>>>(
            slotB, gw3b, b3_bn1, b3_gcn_b, adjp, nullptr, slotE);
        gemm_plain_kernel<256, 0, 0><<<dim3(mt, 2), 256, 0, stream>>>(
            slotA, rw3b, nullptr, nullptr, adjp, b3_res_b, slotF);
        gemm_conv_kernel<256, 256, 1><<<dim3(mt, 2), 256, 0, stream>>>(
            slotE, wt3b, b3_bn2, b3_tcn_b, slotF, nullptr, pooled + (size_t)b0 * 256);
    }

    head_kernel<<<B_, 256, 0, stream>>>(pooled, out_w, out_b, (float*)d_out);
}

// Round 4
// 723.218 us; speedup vs baseline: 10.9407x; 1.0214x over previous
//
#include <hip/hip_runtime.h>
#include <math.h>

#define J_ 24
#define T_ 256
#define B_ 32

typedef short short8v __attribute__((ext_vector_type(8)));   // 8 x bf16 (4 VGPR)
typedef float f32x4  __attribute__((ext_vector_type(4)));    // MFMA acc

__device__ __forceinline__ short f2bf(float f) {
    unsigned u = __float_as_uint(f);
    u += 0x7fffu + ((u >> 16) & 1u);          // round-to-nearest-even
    return (short)(u >> 16);
}
__device__ __forceinline__ float bf2f(short s) {
    return __uint_as_float(((unsigned)(unsigned short)s) << 16);
}

__device__ __constant__ int d_parent[24] = {-1,0,0,0,1,2,3,4,5,6,7,8,9,9,9,12,13,14,16,17,18,19,20,21};

// ---------------------------------------------------------------- adjacency tables
// adjp[0..575]   dense ADJ[j][k] (row-normalized)
// adjp[576..599] colsum[k]
// adjp[600..791] CSR col weights  (24 cols x 8)
// adjp[792..983] CSR col row-idx  (as float)
__global__ void adj_init_kernel(float* __restrict__ adj_out) {
    __shared__ float s_adj[576];
    const int tid = threadIdx.x;
    for (int i = tid; i < 576; i += 256) {
        const int j = i / 24, k = i % 24;
        float a = (j == k || d_parent[k] == j || d_parent[j] == k) ? 1.f : 0.f;
        float d = 0.f;
        for (int kk = 0; kk < 24; ++kk)
            d += (j == kk || d_parent[kk] == j || d_parent[j] == kk) ? 1.f : 0.f;
        const float v = a / fmaxf(d, 1.f);
        s_adj[i] = v;
        adj_out[i] = v;
    }
    __syncthreads();
    if (tid < 24) {
        float cs = 0.f;
        for (int j = 0; j < 24; ++j) cs += s_adj[j*24 + tid];
        adj_out[576 + tid] = cs;
        int n = 0;
        for (int j = 0; j < 24; ++j) {
            const float w = s_adj[j*24 + tid];
            if (w != 0.f && n < 8) {
                adj_out[600 + tid*8 + n] = w;
                adj_out[792 + tid*8 + n] = (float)j;
                ++n;
            }
        }
        for (; n < 8; ++n) { adj_out[600 + tid*8 + n] = 0.f; adj_out[792 + tid*8 + n] = 0.f; }
    }
}

// ---------------------------------------------------------------- fused weight prep
// wt: [O][C][3][1] -> [O][dt*C+c] * s(bn2) ; gw: [O][C] * s(bn1) ; rw3: plain bf16
__global__ __launch_bounds__(256) void prep_kernel(
    const float* __restrict__ w1t, const float* __restrict__ bn1_2,
    const float* __restrict__ w2t, const float* __restrict__ bn2_2,
    const float* __restrict__ w3t, const float* __restrict__ bn3_2,
    const float* __restrict__ g2w, const float* __restrict__ bn2_1,
    const float* __restrict__ g3w, const float* __restrict__ bn3_1,
    const float* __restrict__ r3w,
    short* __restrict__ wt1b, short* __restrict__ wt2b, short* __restrict__ wt3b,
    short* __restrict__ gw2b, short* __restrict__ gw3b, short* __restrict__ rw3b)
{
    const int i = blockIdx.x * 256 + threadIdx.x;
    if (i < 49152) {
        const int o = i / 384, r = i % 384, dt = r / 128, c = r % 128;
        const float s = bn1_2[o] * rsqrtf(bn1_2[384 + o] + 1e-5f);
        wt1b[i] = f2bf(s * w1t[(o*128 + c)*3 + dt]);
    } else if (i < 98304) {
        const int j = i - 49152;
        const int o = j / 384, r = j % 384, dt = r / 128, c = r % 128;
        const float s = bn2_2[o] * rsqrtf(bn2_2[384 + o] + 1e-5f);
        wt2b[j] = f2bf(s * w2t[(o*128 + c)*3 + dt]);
    } else if (i < 294912) {
        const int j = i - 98304;
        const int o = j / 768, r = j % 768, dt = r / 256, c = r % 256;
        const float s = bn3_2[o] * rsqrtf(bn3_2[768 + o] + 1e-5f);
        wt3b[j] = f2bf(s * w3t[(o*256 + c)*3 + dt]);
    } else if (i < 311296) {
        const int j = i - 294912;
        const int o = j / 128;
        const float s = bn2_1[o] * rsqrtf(bn2_1[384 + o] + 1e-5f);
        gw2b[j] = f2bf(s * g2w[j]);
    } else if (i < 344064) {
        const int j = i - 311296;
        const int o = j / 128;
        const float s = bn3_1[o] * rsqrtf(bn3_1[768 + o] + 1e-5f);
        gw3b[j] = f2bf(s * g3w[j]);
    } else if (i < 376832) {
        const int j = i - 344064;
        rw3b[j] = f2bf(r3w[j]);
    }
}

// ================================================================ KERNEL 1
// per 96-row slab-aligned tile: rot6d + premix6 + gcn1 (144 halo rows, VALU)
// -> conv1 MFMA (K=384) + R1 + relu -> f1 (global + LDS)
// -> premix(f1) -> gcn2 MFMA (K=128) + adj-bias + relu -> h2 (global)
__global__ __launch_bounds__(256) void block1_kernel(
    const float* __restrict__ x,
    const float* __restrict__ gw1, const float* __restrict__ gb1, const float* __restrict__ bn1,
    const float* __restrict__ rw1, const float* __restrict__ rb1,
    const float* __restrict__ bn12, const float* __restrict__ tb1, const short* __restrict__ wt1b,
    const short* __restrict__ gw2b, const float* __restrict__ gb2, const float* __restrict__ bn21,
    const float* __restrict__ adjp,
    short* __restrict__ f1_out, short* __restrict__ h2_out)
{
    __shared__ char smem[63072];
    // regions: [0,36864) h1s swizzled 144x256B  (aliased later: f1raw [96][136] bf16)
    //          [36864,61440) fa swizzled 96x256B (aliased early: x6 [144][6] f32 @36864, xa6 @40320)
    //          [61440,62208) cw, [62208,62976) cidx(int), [62976,63072) cs
    float* s_x6  = (float*)(smem + 36864);
    float* s_xa6 = (float*)(smem + 40320);
    float* s_cw  = (float*)(smem + 61440);
    int*   s_ci  = (int*)  (smem + 62208);
    float* s_cs  = (float*)(smem + 62976);

    const int r0 = blockIdx.x * 96;
    const int bstart = (r0 / 6144) * 6144;
    const int bend = bstart + 6144;
    const int tid = threadIdx.x;
    const int l = tid & 63, wid = tid >> 6;
    const int m0w = (wid >> 1) * 48, n0w = (wid & 1) * 64;
    const int lr = l & 15, lk = l >> 4;

    // tables
    if (tid < 192) {
        s_cw[tid] = adjp[600 + tid];
        s_ci[tid] = (int)adjp[792 + tid];
    } else if (tid < 216) {
        s_cs[tid - 192] = adjp[576 + (tid - 192)];
    }
    // phase A: rot6d for 144 halo rows
    if (tid < 144) {
        const int gr = r0 - 24 + tid;
        float o0=0,o1=0,o2=0,o3=0,o4=0,o5=0;
        if (gr >= bstart && gr < bend) {
            const float ax = x[gr*3+0], ay = x[gr*3+1], az = x[gr*3+2];
            const float angle = sqrtf(ax*ax + ay*ay + az*az);
            const float inv = 1.f / (angle + 1e-8f);
            const float ux = ax*inv, uy = ay*inv, uz = az*inv;
            const float c = cosf(angle), s = sinf(angle), omc = 1.f - c;
            o0 = c + omc*ux*ux;  o1 = omc*ux*uy - s*uz;
            o2 = omc*uy*ux + s*uz; o3 = c + omc*uy*uy;
            o4 = omc*uz*ux - s*uy; o5 = omc*uz*uy + s*ux;
        }
        float* p = s_x6 + tid*6;
        p[0]=o0; p[1]=o1; p[2]=o2; p[3]=o3; p[4]=o4; p[5]=o5;
    }
    __syncthreads();
    // phase B: premix6 (CSR)
    for (int idx = tid; idx < 864; idx += 256) {
        const int hr = idx / 6, c = idx % 6;
        const int k = hr % 24, sl = (hr / 24) * 24;
        float a = 0.f;
        #pragma unroll
        for (int u = 0; u < 8; ++u)
            a = fmaf(s_cw[k*8+u], s_x6[(sl + s_ci[k*8+u])*6 + c], a);
        s_xa6[hr*6 + c] = a;
    }
    __syncthreads();
    // phase C: gcn1 -> h1s (bf16 swizzled, zero outside batch)
    {
        const int o = tid & 127, half = tid >> 7;
        const float s1 = bn1[o] * rsqrtf(bn1[384 + o] + 1e-5f);
        const float t1 = bn1[128 + o] - bn1[256 + o] * s1;
        const float g1 = s1 * gb1[o];
        float wg[6];
        #pragma unroll
        for (int c = 0; c < 6; ++c) wg[c] = gw1[o*6 + c];
        for (int hr = half; hr < 144; hr += 2) {
            const int gr = r0 - 24 + hr;
            short hv = 0;
            if (gr >= bstart && gr < bend) {
                float a = 0.f;
                #pragma unroll
                for (int c = 0; c < 6; ++c) a = fmaf(s_xa6[hr*6 + c], wg[c], a);
                hv = f2bf(fmaxf(s1*a + t1 + g1*s_cs[hr % 24], 0.f));
            }
            *(short*)(smem + hr*256 + ((((o*2)&0xF0)) ^ ((hr&7)<<4)) + ((o*2)&14)) = hv;
        }
    }
    __syncthreads();
    // phase D: conv1 MFMA  K = 3 x 128
    f32x4 acc[3][4];
    #pragma unroll
    for (int mi = 0; mi < 3; ++mi)
        #pragma unroll
        for (int ni = 0; ni < 4; ++ni) acc[mi][ni] = (f32x4){0.f,0.f,0.f,0.f};
    #pragma unroll
    for (int dt = 0; dt < 3; ++dt) {
        #pragma unroll
        for (int kc = 0; kc < 4; ++kc) {
            short8v bfr[4], afr[3];
            #pragma unroll
            for (int ni = 0; ni < 4; ++ni) {
                const int n = n0w + ni*16 + lr;
                bfr[ni] = *(const short8v*)(wt1b + (size_t)n*384 + dt*128 + kc*32 + lk*8);
            }
            #pragma unroll
            for (int mi = 0; mi < 3; ++mi) {
                const int row = m0w + dt*24 + mi*16 + lr;
                afr[mi] = *(const short8v*)(smem + row*256 + ((kc*64 + lk*16) ^ ((row&7)<<4)));
            }
            #pragma unroll
            for (int mi = 0; mi < 3; ++mi)
                #pragma unroll
                for (int ni = 0; ni < 4; ++ni)
                    acc[mi][ni] = __builtin_amdgcn_mfma_f32_16x16x32_bf16(afr[mi], bfr[ni], acc[mi][ni], 0, 0, 0);
        }
    }
    __syncthreads();   // all frags consumed; h1s region may be reused
    // phase E: epilogue conv1 + R1 -> f1 (global + f1raw LDS)
    #pragma unroll
    for (int ni = 0; ni < 4; ++ni) {
        const int o = n0w + ni*16 + lr;
        const float s2 = bn12[o] * rsqrtf(bn12[384 + o] + 1e-5f);
        const float bias = (bn12[128 + o] - bn12[256 + o]*s2) + s2*tb1[o];
        float wr[6];
        #pragma unroll
        for (int c = 0; c < 6; ++c) wr[c] = rw1[o*6 + c];
        const float rb = rb1[o];
        #pragma unroll
        for (int mi = 0; mi < 3; ++mi)
            #pragma unroll
            for (int rg = 0; rg < 4; ++rg) {
                const int rl = m0w + mi*16 + lk*4 + rg;
                float r = rb;
                #pragma unroll
                for (int c = 0; c < 6; ++c) r = fmaf(s_x6[(rl+24)*6 + c], wr[c], r);
                const float v = fmaxf(acc[mi][ni][rg] + bias + r, 0.f);
                const short hv = f2bf(v);
                f1_out[(size_t)(r0 + rl)*128 + o] = hv;
                *(short*)(smem + rl*272 + o*2) = hv;
            }
    }
    __syncthreads();
    // phase F: premix f1 (CSR, 8-ch vectors) -> fa swizzled
    for (int task = tid; task < 96*16; task += 256) {
        const int row = task >> 4, cg = task & 15;
        const int k = row % 24, sl = (row / 24) * 24;
        float a[8] = {0,0,0,0,0,0,0,0};
        #pragma unroll
        for (int u = 0; u < 8; ++u) {
            const float wgt = s_cw[k*8+u];
            const short8v v = *(const short8v*)(smem + (sl + s_ci[k*8+u])*272 + cg*16);
            #pragma unroll
            for (int e = 0; e < 8; ++e) a[e] = fmaf(wgt, bf2f(v[e]), a[e]);
        }
        short8v o8;
        #pragma unroll
        for (int e = 0; e < 8; ++e) o8[e] = f2bf(a[e]);
        *(short8v*)(smem + 36864 + row*256 + ((cg*16) ^ ((row&7)<<4))) = o8;
    }
    __syncthreads();
    // phase G: gcn2 MFMA  K=128
    #pragma unroll
    for (int mi = 0; mi < 3; ++mi)
        #pragma unroll
        for (int ni = 0; ni < 4; ++ni) acc[mi][ni] = (f32x4){0.f,0.f,0.f,0.f};
    #pragma unroll
    for (int kc = 0; kc < 4; ++kc) {
        short8v bfr[4], afr[3];
        #pragma unroll
        for (int ni = 0; ni < 4; ++ni) {
            const int n = n0w + ni*16 + lr;
            bfr[ni] = *(const short8v*)(gw2b + (size_t)n*128 + kc*32 + lk*8);
        }
        #pragma unroll
        for (int mi = 0; mi < 3; ++mi) {
            const int row = m0w + mi*16 + lr;
            afr[mi] = *(const short8v*)(smem + 36864 + row*256 + ((kc*64 + lk*16) ^ ((row&7)<<4)));
        }
        #pragma unroll
        for (int mi = 0; mi < 3; ++mi)
            #pragma unroll
            for (int ni = 0; ni < 4; ++ni)
                acc[mi][ni] = __builtin_amdgcn_mfma_f32_16x16x32_bf16(afr[mi], bfr[ni], acc[mi][ni], 0, 0, 0);
    }
    #pragma unroll
    for (int ni = 0; ni < 4; ++ni) {
        const int o = n0w + ni*16 + lr;
        const float s = bn21[o] * rsqrtf(bn21[384 + o] + 1e-5f);
        const float t = bn21[128 + o] - bn21[256 + o]*s;
        const float g = s * gb2[o];
        #pragma unroll
        for (int mi = 0; mi < 3; ++mi)
            #pragma unroll
            for (int rg = 0; rg < 4; ++rg) {
                const int rl = m0w + mi*16 + lk*4 + rg;
                const float v = fmaxf(acc[mi][ni][rg] + t + g*s_cs[rl % 24], 0.f);
                h2_out[(size_t)(r0 + rl)*128 + o] = f2bf(v);
            }
    }
}

// ================================================================ KERNEL 2
// stage h2 halo -> conv2 MFMA (K=384) + f1 residual + relu -> f2 (LDS only)
// -> premix(f2) -> gcn3 MFMA (K=128, N=256) -> h3 ; R3 = f2 @ rw3 + rb3 -> R3
__global__ __launch_bounds__(256) void block2_kernel(
    const short* __restrict__ h2, const short* __restrict__ wt2b,
    const float* __restrict__ bn22, const float* __restrict__ tb2,
    const short* __restrict__ f1,
    const short* __restrict__ gw3b, const float* __restrict__ gb3, const float* __restrict__ bn31,
    const short* __restrict__ rw3b, const float* __restrict__ rb3,
    const float* __restrict__ adjp,
    short* __restrict__ h3_out, short* __restrict__ R3_out)
{
    __shared__ char smem[63072];
    float* s_cw  = (float*)(smem + 61440);
    int*   s_ci  = (int*)  (smem + 62208);
    float* s_cs  = (float*)(smem + 62976);

    const int r0 = blockIdx.x * 96;
    const int bstart = (r0 / 6144) * 6144;
    const int bend = bstart + 6144;
    const int tid = threadIdx.x;
    const int l = tid & 63, wid = tid >> 6;
    const int m0w = (wid >> 1) * 48;
    const int lr = l & 15, lk = l >> 4;

    if (tid < 192) {
        s_cw[tid] = adjp[600 + tid];
        s_ci[tid] = (int)adjp[792 + tid];
    } else if (tid < 216) {
        s_cs[tid - 192] = adjp[576 + (tid - 192)];
    }
    // stage h2 halo (144 x 128) swizzled
    for (int ch = tid; ch < 144*16; ch += 256) {
        const int row = ch >> 4, cg = ch & 15;
        const int gr = r0 - 24 + row;
        float4 v = make_float4(0.f,0.f,0.f,0.f);
        if (gr >= bstart && gr < bend)
            v = *(const float4*)(h2 + (size_t)gr*128 + cg*8);
        *(float4*)(smem + row*256 + ((cg*16) ^ ((row&7)<<4))) = v;
    }
    __syncthreads();
    // conv2 MFMA
    {
        const int n0w = (wid & 1) * 64;
        f32x4 acc[3][4];
        #pragma unroll
        for (int mi = 0; mi < 3; ++mi)
            #pragma unroll
            for (int ni = 0; ni < 4; ++ni) acc[mi][ni] = (f32x4){0.f,0.f,0.f,0.f};
        #pragma unroll
        for (int dt = 0; dt < 3; ++dt) {
            #pragma unroll
            for (int kc = 0; kc < 4; ++kc) {
                short8v bfr[4], afr[3];
                #pragma unroll
                for (int ni = 0; ni < 4; ++ni) {
                    const int n = n0w + ni*16 + lr;
                    bfr[ni] = *(const short8v*)(wt2b + (size_t)n*384 + dt*128 + kc*32 + lk*8);
                }
                #pragma unroll
                for (int mi = 0; mi < 3; ++mi) {
                    const int row = m0w + dt*24 + mi*16 + lr;
                    afr[mi] = *(const short8v*)(smem + row*256 + ((kc*64 + lk*16) ^ ((row&7)<<4)));
                }
                #pragma unroll
                for (int mi = 0; mi < 3; ++mi)
                    #pragma unroll
                    for (int ni = 0; ni < 4; ++ni)
                        acc[mi][ni] = __builtin_amdgcn_mfma_f32_16x16x32_bf16(afr[mi], bfr[ni], acc[mi][ni], 0, 0, 0);
            }
        }
        __syncthreads();   // h2s dead
        // epilogue: + bias + f1 residual, relu -> f2raw LDS [96][136]
        #pragma unroll
        for (int ni = 0; ni < 4; ++ni) {
            const int o = n0w + ni*16 + lr;
            const float s = bn22[o] * rsqrtf(bn22[384 + o] + 1e-5f);
            const float bias = (bn22[128 + o] - bn22[256 + o]*s) + s*tb2[o];
            #pragma unroll
            for (int mi = 0; mi < 3; ++mi)
                #pragma unroll
                for (int rg = 0; rg < 4; ++rg) {
                    const int rl = m0w + mi*16 + lk*4 + rg;
                    const float res = bf2f(f1[(size_t)(r0 + rl)*128 + o]);
                    const float v = fmaxf(acc[mi][ni][rg] + bias + res, 0.f);
                    *(short*)(smem + rl*272 + o*2) = f2bf(v);
                }
        }
    }
    __syncthreads();
    // premix f2 -> fa swizzled
    for (int task = tid; task < 96*16; task += 256) {
        const int row = task >> 4, cg = task & 15;
        const int k = row % 24, sl = (row / 24) * 24;
        float a[8] = {0,0,0,0,0,0,0,0};
        #pragma unroll
        for (int u = 0; u < 8; ++u) {
            const float wgt = s_cw[k*8+u];
            const short8v v = *(const short8v*)(smem + (sl + s_ci[k*8+u])*272 + cg*16);
            #pragma unroll
            for (int e = 0; e < 8; ++e) a[e] = fmaf(wgt, bf2f(v[e]), a[e]);
        }
        short8v o8;
        #pragma unroll
        for (int e = 0; e < 8; ++e) o8[e] = f2bf(a[e]);
        *(short8v*)(smem + 36864 + row*256 + ((cg*16) ^ ((row&7)<<4))) = o8;
    }
    __syncthreads();
    // gcn3 MFMA: N=256, A=fa
    {
        const int n0w = (wid & 1) * 128;
        f32x4 acc[3][8];
        #pragma unroll
        for (int mi = 0; mi < 3; ++mi)
            #pragma unroll
            for (int ni = 0; ni < 8; ++ni) acc[mi][ni] = (f32x4){0.f,0.f,0.f,0.f};
        #pragma unroll
        for (int kc = 0; kc < 4; ++kc) {
            short8v bfr[8], afr[3];
            #pragma unroll
            for (int ni = 0; ni < 8; ++ni) {
                const int n = n0w + ni*16 + lr;
                bfr[ni] = *(const short8v*)(gw3b + (size_t)n*128 + kc*32 + lk*8);
            }
            #pragma unroll
            for (int mi = 0; mi < 3; ++mi) {
                const int row = m0w + mi*16 + lr;
                afr[mi] = *(const short8v*)(smem + 36864 + row*256 + ((kc*64 + lk*16) ^ ((row&7)<<4)));
            }
            #pragma unroll
            for (int mi = 0; mi < 3; ++mi)
                #pragma unroll
                for (int ni = 0; ni < 8; ++ni)
                    acc[mi][ni] = __builtin_amdgcn_mfma_f32_16x16x32_bf16(afr[mi], bfr[ni], acc[mi][ni], 0, 0, 0);
        }
        #pragma unroll
        for (int ni = 0; ni < 8; ++ni) {
            const int o = n0w + ni*16 + lr;
            const float s = bn31[o] * rsqrtf(bn31[768 + o] + 1e-5f);
            const float t = bn31[256 + o] - bn31[512 + o]*s;
            const float g = s * gb3[o];
            #pragma unroll
            for (int mi = 0; mi < 3; ++mi)
                #pragma unroll
                for (int rg = 0; rg < 4; ++rg) {
                    const int rl = m0w + mi*16 + lk*4 + rg;
                    const float v = fmaxf(acc[mi][ni][rg] + t + g*s_cs[rl % 24], 0.f);
                    h3_out[(size_t)(r0 + rl)*256 + o] = f2bf(v);
                }
        }
        // R3 MFMA from raw f2raw
        #pragma unroll
        for (int mi = 0; mi < 3; ++mi)
            #pragma unroll
            for (int ni = 0; ni < 8; ++ni) acc[mi][ni] = (f32x4){0.f,0.f,0.f,0.f};
        #pragma unroll
        for (int kc = 0; kc < 4; ++kc) {
            short8v bfr[8], afr[3];
            #pragma unroll
            for (int ni = 0; ni < 8; ++ni) {
                const int n = n0w + ni*16 + lr;
                bfr[ni] = *(const short8v*)(rw3b + (size_t)n*128 + kc*32 + lk*8);
            }
            #pragma unroll
            for (int mi = 0; mi < 3; ++mi) {
                const int row = m0w + mi*16 + lr;
                afr[mi] = *(const short8v*)(smem + row*272 + kc*64 + lk*16);
            }
            #pragma unroll
            for (int mi = 0; mi < 3; ++mi)
                #pragma unroll
                for (int ni = 0; ni < 8; ++ni)
                    acc[mi][ni] = __builtin_amdgcn_mfma_f32_16x16x32_bf16(afr[mi], bfr[ni], acc[mi][ni], 0, 0, 0);
        }
        #pragma unroll
        for (int ni = 0; ni < 8; ++ni) {
            const int o = n0w + ni*16 + lr;
            const float rb = rb3[o];
            #pragma unroll
            for (int mi = 0; mi < 3; ++mi)
                #pragma unroll
                for (int rg = 0; rg < 4; ++rg) {
                    const int rl = m0w + mi*16 + lk*4 + rg;
                    R3_out[(size_t)(r0 + rl)*256 + o] = f2bf(acc[mi][ni][rg] + rb);
                }
        }
    }
}

// ================================================================ KERNEL 3 (round-3 verified)
// conv3 + BN + R3 residual + relu + mean-pool (atomics)
__global__ __launch_bounds__(256) void conv3_pool_kernel(
    const short* __restrict__ A, const short* __restrict__ Bw,
    const float* __restrict__ bn, const float* __restrict__ tb,
    const short* __restrict__ Res, float* __restrict__ pooled)
{
    __shared__ short lds[176 * 128];
    const int r0 = blockIdx.x * 128, n0 = blockIdx.y * 128;
    const int bb = r0 / 6144;
    const int bstart = bb * 6144, bend = bstart + 6144;
    const int tid = threadIdx.x, l = tid & 63, wid = tid >> 6;
    const int m0w = (wid >> 1) * 64, n0w = (wid & 1) * 64;
    const int lr = l & 15, lk = l >> 4;

    f32x4 acc[4][4];
    #pragma unroll
    for (int mi = 0; mi < 4; ++mi)
        #pragma unroll
        for (int ni = 0; ni < 4; ++ni) acc[mi][ni] = (f32x4){0.f,0.f,0.f,0.f};

    for (int p = 0; p < 2; ++p) {
        if (p) __syncthreads();
        for (int ch = tid; ch < 176 * 16; ch += 256) {
            const int row = ch >> 4, c16 = ch & 15;
            const int gr = r0 - 24 + row;
            float4 v = make_float4(0.f,0.f,0.f,0.f);
            if (gr >= bstart && gr < bend)
                v = *(const float4*)(A + (size_t)gr * 256 + p * 128 + c16 * 8);
            *(float4*)((char*)lds + row * 256 + ((c16 * 16) ^ ((row & 7) << 4))) = v;
        }
        __syncthreads();
        #pragma unroll
        for (int dt = 0; dt < 3; ++dt) {
            #pragma unroll
            for (int kc = 0; kc < 4; ++kc) {
                short8v bfr[4], afr[4];
                #pragma unroll
                for (int ni = 0; ni < 4; ++ni) {
                    const int n = n0 + n0w + ni * 16 + lr;
                    bfr[ni] = *(const short8v*)(Bw + (size_t)n * 768 + dt * 256 + p * 128 + kc * 32 + lk * 8);
                }
                #pragma unroll
                for (int mi = 0; mi < 4; ++mi) {
                    const int row = m0w + dt * 24 + mi * 16 + lr;
                    afr[mi] = *(const short8v*)((char*)lds + row * 256 + ((kc * 64 + lk * 16) ^ ((row & 7) << 4)));
                }
                #pragma unroll
                for (int mi = 0; mi < 4; ++mi)
                    #pragma unroll
                    for (int ni = 0; ni < 4; ++ni)
                        acc[mi][ni] = __builtin_amdgcn_mfma_f32_16x16x32_bf16(afr[mi], bfr[ni], acc[mi][ni], 0, 0, 0);
            }
        }
    }

    float psum[4] = {0.f, 0.f, 0.f, 0.f};
    #pragma unroll
    for (int ni = 0; ni < 4; ++ni) {
        const int o = n0 + n0w + ni * 16 + lr;
        const float s = bn[o] * rsqrtf(bn[768 + o] + 1e-5f);
        const float t = bn[256 + o] - bn[512 + o] * s;
        const float bias = s * tb[o] + t;
        #pragma unroll
        for (int mi = 0; mi < 4; ++mi)
            #pragma unroll
            for (int rg = 0; rg < 4; ++rg) {
                const int rl = m0w + mi * 16 + lk * 4 + rg;
                float v = acc[mi][ni][rg] + bias;
                v += bf2f(Res[(size_t)(r0 + rl) * 256 + o]);
                v = fmaxf(v, 0.f);
                psum[ni] += v;
            }
    }
    #pragma unroll
    for (int ni = 0; ni < 4; ++ni) {
        float v = psum[ni];
        v += __shfl_xor(v, 16);
        v += __shfl_xor(v, 32);
        if (l < 16) atomicAdd(pooled + (size_t)bb * 256 + (n0 + n0w + ni * 16 + l), v);
    }
}

// ---------------------------------------------------------------- head
__global__ __launch_bounds__(256) void head_kernel(const float* __restrict__ pooled_sums,
    const float* __restrict__ ow, const float* __restrict__ ob, float* __restrict__ outp) {
    __shared__ float pooled[256];
    const int b = blockIdx.x, tid = threadIdx.x;
    pooled[tid] = pooled_sums[(size_t)b*256 + tid] * (1.f/6144.f);
    __syncthreads();
    for (int rep = 0; rep < 2; ++rep) {
        const int oo = rep*256 + tid;
        float a = ob[oo];
        const float4* wr = (const float4*)(ow + (size_t)oo*256);
        for (int c4 = 0; c4 < 64; ++c4) {
            const float4 w = wr[c4];
            const float4 p = *(const float4*)&pooled[c4*4];
            a += w.x*p.x + w.y*p.y + w.z*p.z + w.w*p.w;
        }
        outp[(size_t)b*512 + oo] = a;
    }
}

// ---------------------------------------------------------------- launch
extern "C" void kernel_launch(void* const* d_in, const int* in_sizes, int n_in,
                              void* d_out, int out_size, void* d_ws, size_t ws_size,
                              hipStream_t stream)
{
    const float* x        = (const float*)d_in[0];
    const float* b1_gcn_w = (const float*)d_in[1];
    const float* b1_gcn_b = (const float*)d_in[2];
    const float* b1_bn1   = (const float*)d_in[3];
    const float* b1_tcn_w = (const float*)d_in[4];
    const float* b1_tcn_b = (const float*)d_in[5];
    const float* b1_bn2   = (const float*)d_in[6];
    const float* b1_res_w = (const float*)d_in[7];
    const float* b1_res_b = (const float*)d_in[8];
    const float* b2_gcn_w = (const float*)d_in[9];
    const float* b2_gcn_b = (const float*)d_in[10];
    const float* b2_bn1   = (const float*)d_in[11];
    const float* b2_tcn_w = (const float*)d_in[12];
    const float* b2_tcn_b = (const float*)d_in[13];
    const float* b2_bn2   = (const float*)d_in[14];
    const float* b3_gcn_w = (const float*)d_in[15];
    const float* b3_gcn_b = (const float*)d_in[16];
    const float* b3_bn1   = (const float*)d_in[17];
    const float* b3_tcn_w = (const float*)d_in[18];
    const float* b3_tcn_b = (const float*)d_in[19];
    const float* b3_bn2   = (const float*)d_in[20];
    const float* b3_res_w = (const float*)d_in[21];
    const float* b3_res_b = (const float*)d_in[22];
    const float* out_w    = (const float*)d_in[23];
    const float* out_b    = (const float*)d_in[24];

    // ---- fixed workspace carve
    char* w = (char*)d_ws;
    float* adjp = (float*)w;   w += 4096;            // 984 floats used
    short* wt1b = (short*)w;   w += 98304;           // 128*384
    short* wt2b = (short*)w;   w += 98304;
    short* wt3b = (short*)w;   w += 393216;          // 256*768
    short* gw2b = (short*)w;   w += 32768;           // 128*128
    short* gw3b = (short*)w;   w += 65536;           // 256*128
    short* rw3b = (short*)w;   w += 65536;           // 256*128
    float* pooled = (float*)w; w += 32768;           // 32*256
    const size_t fixed = (size_t)(w - (char*)d_ws);

    // ---- adaptive batch-group: per-G bytes = 6144*2*(128+128+256+256) = 9,437,184
    int G = 1;
    {
        const int tiers[6] = {32, 16, 8, 4, 2, 1};
        for (int ti = 0; ti < 6; ++ti) {
            const size_t need = fixed + (size_t)tiers[ti] * 9437184ull;
            if (need <= ws_size) { G = tiers[ti]; break; }
        }
    }
    const size_t MG = (size_t)G * 6144;

    short* f1 = (short*)w;           // MG*128
    short* h2 = f1 + MG*128;         // MG*128
    short* h3 = h2 + MG*128;         // MG*256
    short* R3 = h3 + MG*256;         // MG*256

    hipMemsetAsync(pooled, 0, 32*256*sizeof(float), stream);
    adj_init_kernel<<<1, 256, 0, stream>>>(adjp);
    prep_kernel<<<1472, 256, 0, stream>>>(b1_tcn_w, b1_bn2, b2_tcn_w, b2_bn2, b3_tcn_w, b3_bn2,
                                          b2_gcn_w, b2_bn1, b3_gcn_w, b3_bn1, b3_res_w,
                                          wt1b, wt2b, wt3b, gw2b, gw3b, rw3b);

    for (int b0 = 0; b0 < B_; b0 += G) {
        block1_kernel<<<64*G, 256, 0, stream>>>(
            x + (size_t)b0*6144*3,
            b1_gcn_w, b1_gcn_b, b1_bn1, b1_res_w, b1_res_b,
            b1_bn2, b1_tcn_b, wt1b,
            gw2b, b2_gcn_b, b2_bn1, adjp, f1, h2);
        block2_kernel<<<64*G, 256, 0, stream>>>(
            h2, wt2b, b2_bn2, b2_tcn_b, f1,
            gw3b, b3_gcn_b, b3_bn1, rw3b, b3_res_b, adjp, h3, R3);
        conv3_pool_kernel<<<dim3(48*G, 2), 256, 0, stream>>>(
            h3, wt3b, b3_bn2, b3_tcn_b, R3, pooled + (size_t)b0*256);
    }

    head_kernel<<<B_, 256, 0, stream>>>(pooled, out_w, out_b, (float*)d_out);
}

// Round 5
// 544.708 us; speedup vs baseline: 14.5262x; 1.3277x over previous
//
#include <hip/hip_runtime.h>
#include <math.h>

#define J_ 24
#define T_ 256
#define B_ 32

typedef short short8v __attribute__((ext_vector_type(8)));   // 8 x bf16 (4 VGPR)
typedef float f32x4  __attribute__((ext_vector_type(4)));    // MFMA acc

__device__ __forceinline__ short f2bf(float f) {
    unsigned u = __float_as_uint(f);
    u += 0x7fffu + ((u >> 16) & 1u);          // round-to-nearest-even
    return (short)(u >> 16);
}
__device__ __forceinline__ float bf2f(short s) {
    return __uint_as_float(((unsigned)(unsigned short)s) << 16);
}

__device__ __constant__ int d_parent[24] = {-1,0,0,0,1,2,3,4,5,6,7,8,9,9,9,12,13,14,16,17,18,19,20,21};

// ---------------------------------------------------------------- adjacency tables
// adjp[0..575] dense ADJ ; [576..599] colsum ; [600..791] CSR wgt (24x8) ; [792..983] CSR idx
__global__ void adj_init_kernel(float* __restrict__ adj_out) {
    __shared__ float s_adj[576];
    const int tid = threadIdx.x;
    for (int i = tid; i < 576; i += 256) {
        const int j = i / 24, k = i % 24;
        float a = (j == k || d_parent[k] == j || d_parent[j] == k) ? 1.f : 0.f;
        float d = 0.f;
        for (int kk = 0; kk < 24; ++kk)
            d += (j == kk || d_parent[kk] == j || d_parent[j] == kk) ? 1.f : 0.f;
        const float v = a / fmaxf(d, 1.f);
        s_adj[i] = v;
        adj_out[i] = v;
    }
    __syncthreads();
    if (tid < 24) {
        float cs = 0.f;
        for (int j = 0; j < 24; ++j) cs += s_adj[j*24 + tid];
        adj_out[576 + tid] = cs;
        int n = 0;
        for (int j = 0; j < 24; ++j) {
            const float w = s_adj[j*24 + tid];
            if (w != 0.f && n < 8) {
                adj_out[600 + tid*8 + n] = w;
                adj_out[792 + tid*8 + n] = (float)j;
                ++n;
            }
        }
        for (; n < 8; ++n) { adj_out[600 + tid*8 + n] = 0.f; adj_out[792 + tid*8 + n] = 0.f; }
    }
}

// ---------------------------------------------------------------- fused weight prep
__global__ __launch_bounds__(256) void prep_kernel(
    const float* __restrict__ w1t, const float* __restrict__ bn1_2,
    const float* __restrict__ w2t, const float* __restrict__ bn2_2,
    const float* __restrict__ w3t, const float* __restrict__ bn3_2,
    const float* __restrict__ g2w, const float* __restrict__ bn2_1,
    const float* __restrict__ g3w, const float* __restrict__ bn3_1,
    const float* __restrict__ r3w,
    short* __restrict__ wt1b, short* __restrict__ wt2b, short* __restrict__ wt3b,
    short* __restrict__ gw2b, short* __restrict__ gw3b, short* __restrict__ rw3b)
{
    const int i = blockIdx.x * 256 + threadIdx.x;
    if (i < 49152) {
        const int o = i / 384, r = i % 384, dt = r / 128, c = r % 128;
        const float s = bn1_2[o] * rsqrtf(bn1_2[384 + o] + 1e-5f);
        wt1b[i] = f2bf(s * w1t[(o*128 + c)*3 + dt]);
    } else if (i < 98304) {
        const int j = i - 49152;
        const int o = j / 384, r = j % 384, dt = r / 128, c = r % 128;
        const float s = bn2_2[o] * rsqrtf(bn2_2[384 + o] + 1e-5f);
        wt2b[j] = f2bf(s * w2t[(o*128 + c)*3 + dt]);
    } else if (i < 294912) {
        const int j = i - 98304;
        const int o = j / 768, r = j % 768, dt = r / 256, c = r % 256;
        const float s = bn3_2[o] * rsqrtf(bn3_2[768 + o] + 1e-5f);
        wt3b[j] = f2bf(s * w3t[(o*256 + c)*3 + dt]);
    } else if (i < 311296) {
        const int j = i - 294912;
        const int o = j / 128;
        const float s = bn2_1[o] * rsqrtf(bn2_1[384 + o] + 1e-5f);
        gw2b[j] = f2bf(s * g2w[j]);
    } else if (i < 344064) {
        const int j = i - 311296;
        const int o = j / 128;
        const float s = bn3_1[o] * rsqrtf(bn3_1[768 + o] + 1e-5f);
        gw3b[j] = f2bf(s * g3w[j]);
    } else if (i < 376832) {
        const int j = i - 344064;
        rw3b[j] = f2bf(r3w[j]);
    }
}

// LDS layout (block1/block2), 52,320 B total -> 3 blocks/CU:
//   [0,36864)      h-stage swizzled (144 rows x 256B) ; later f-raw [96][136] bf16 at [0,26112)
//   [26112,50688)  fa swizzled (96 x 256B)  (block1: x6@40320, xa6@44176 alias, dead before fa write)
//   [50688,52320)  tables: cw[192] ci[192] cs[24]
#define LDS_SZ   52320
#define FA_OFF   26112
#define X6_OFF   40320
#define XA6_OFF  44176
#define TBL_OFF  50688

// ================================================================ KERNEL 1 (512 thr, 8 waves)
__global__ __launch_bounds__(512) void block1_kernel(
    const float* __restrict__ x,
    const float* __restrict__ gw1, const float* __restrict__ gb1, const float* __restrict__ bn1,
    const float* __restrict__ rw1, const float* __restrict__ rb1,
    const float* __restrict__ bn12, const float* __restrict__ tb1, const short* __restrict__ wt1b,
    const short* __restrict__ gw2b, const float* __restrict__ gb2, const float* __restrict__ bn21,
    const float* __restrict__ adjp,
    short* __restrict__ f1_out, short* __restrict__ h2_out)
{
    __shared__ char smem[LDS_SZ];
    float* s_x6  = (float*)(smem + X6_OFF);
    float* s_xa6 = (float*)(smem + XA6_OFF);
    float* s_cw  = (float*)(smem + TBL_OFF);
    int*   s_ci  = (int*)  (smem + TBL_OFF + 768);
    float* s_cs  = (float*)(smem + TBL_OFF + 1536);

    const int r0 = blockIdx.x * 96;
    const int bstart = (r0 / 6144) * 6144;
    const int bend = bstart + 6144;
    const int tid = threadIdx.x;
    const int l = tid & 63, wid = tid >> 6;
    const int m0w = (wid >> 2) * 48;          // 2-way M split (48 rows, 3 frags)
    const int n0w = (wid & 3) * 32;           // 4-way N split (32 cols, 2 frags)
    const int lr = l & 15, lk = l >> 4;

    if (tid < 192) { s_cw[tid] = adjp[600 + tid]; s_ci[tid] = (int)adjp[792 + tid]; }
    else if (tid < 216) s_cs[tid - 192] = adjp[576 + (tid - 192)];
    // phase A: rot6d, 144 halo rows
    if (tid < 144) {
        const int gr = r0 - 24 + tid;
        float o0=0,o1=0,o2=0,o3=0,o4=0,o5=0;
        if (gr >= bstart && gr < bend) {
            const float ax = x[gr*3+0], ay = x[gr*3+1], az = x[gr*3+2];
            const float angle = sqrtf(ax*ax + ay*ay + az*az);
            const float inv = 1.f / (angle + 1e-8f);
            const float ux = ax*inv, uy = ay*inv, uz = az*inv;
            const float c = cosf(angle), s = sinf(angle), omc = 1.f - c;
            o0 = c + omc*ux*ux;   o1 = omc*ux*uy - s*uz;
            o2 = omc*uy*ux + s*uz; o3 = c + omc*uy*uy;
            o4 = omc*uz*ux - s*uy; o5 = omc*uz*uy + s*ux;
        }
        float* p = s_x6 + tid*6;
        p[0]=o0; p[1]=o1; p[2]=o2; p[3]=o3; p[4]=o4; p[5]=o5;
    }
    __syncthreads();
    // phase B: premix6 (CSR)
    for (int idx = tid; idx < 864; idx += 512) {
        const int hr = idx / 6, c = idx % 6;
        const int k = hr % 24, sl = (hr / 24) * 24;
        float a = 0.f;
        #pragma unroll
        for (int u = 0; u < 8; ++u)
            a = fmaf(s_cw[k*8+u], s_x6[(sl + s_ci[k*8+u])*6 + c], a);
        s_xa6[hr*6 + c] = a;
    }
    __syncthreads();
    // phase C: gcn1 -> h1s swizzled bf16
    {
        const int o = tid & 127, q = tid >> 7;
        const float s1 = bn1[o] * rsqrtf(bn1[384 + o] + 1e-5f);
        const float t1 = bn1[128 + o] - bn1[256 + o] * s1;
        const float g1 = s1 * gb1[o];
        float wg[6];
        #pragma unroll
        for (int c = 0; c < 6; ++c) wg[c] = gw1[o*6 + c];
        for (int hr = q; hr < 144; hr += 4) {
            const int gr = r0 - 24 + hr;
            short hv = 0;
            if (gr >= bstart && gr < bend) {
                float a = 0.f;
                #pragma unroll
                for (int c = 0; c < 6; ++c) a = fmaf(s_xa6[hr*6 + c], wg[c], a);
                hv = f2bf(fmaxf(s1*a + t1 + g1*s_cs[hr % 24], 0.f));
            }
            *(short*)(smem + hr*256 + ((((o*2)&0xF0)) ^ ((hr&7)<<4)) + ((o*2)&14)) = hv;
        }
    }
    __syncthreads();
    // phase D: conv1 MFMA  K=3x128
    f32x4 acc[3][2];
    #pragma unroll
    for (int mi = 0; mi < 3; ++mi)
        #pragma unroll
        for (int ni = 0; ni < 2; ++ni) acc[mi][ni] = (f32x4){0.f,0.f,0.f,0.f};
    #pragma unroll
    for (int dt = 0; dt < 3; ++dt) {
        #pragma unroll
        for (int kc = 0; kc < 4; ++kc) {
            short8v bfr[2], afr[3];
            #pragma unroll
            for (int ni = 0; ni < 2; ++ni) {
                const int n = n0w + ni*16 + lr;
                bfr[ni] = *(const short8v*)(wt1b + (size_t)n*384 + dt*128 + kc*32 + lk*8);
            }
            #pragma unroll
            for (int mi = 0; mi < 3; ++mi) {
                const int row = m0w + dt*24 + mi*16 + lr;
                afr[mi] = *(const short8v*)(smem + row*256 + ((kc*64 + lk*16) ^ ((row&7)<<4)));
            }
            #pragma unroll
            for (int mi = 0; mi < 3; ++mi)
                #pragma unroll
                for (int ni = 0; ni < 2; ++ni)
                    acc[mi][ni] = __builtin_amdgcn_mfma_f32_16x16x32_bf16(afr[mi], bfr[ni], acc[mi][ni], 0, 0, 0);
        }
    }
    __syncthreads();
    // phase E: epilogue conv1 + R1(fp32 VALU) -> f1 global + f1raw LDS
    #pragma unroll
    for (int ni = 0; ni < 2; ++ni) {
        const int o = n0w + ni*16 + lr;
        const float s2 = bn12[o] * rsqrtf(bn12[384 + o] + 1e-5f);
        const float bias = (bn12[128 + o] - bn12[256 + o]*s2) + s2*tb1[o];
        float wr[6];
        #pragma unroll
        for (int c = 0; c < 6; ++c) wr[c] = rw1[o*6 + c];
        const float rb = rb1[o];
        #pragma unroll
        for (int mi = 0; mi < 3; ++mi)
            #pragma unroll
            for (int rg = 0; rg < 4; ++rg) {
                const int rl = m0w + mi*16 + lk*4 + rg;
                float r = rb;
                #pragma unroll
                for (int c = 0; c < 6; ++c) r = fmaf(s_x6[(rl+24)*6 + c], wr[c], r);
                const short hv = f2bf(fmaxf(acc[mi][ni][rg] + bias + r, 0.f));
                f1_out[(size_t)(r0 + rl)*128 + o] = hv;
                *(short*)(smem + rl*272 + o*2) = hv;
            }
    }
    __syncthreads();
    // phase F: premix f1 -> fa swizzled
    for (int task = tid; task < 96*16; task += 512) {
        const int row = task >> 4, cg = task & 15;
        const int k = row % 24, sl = (row / 24) * 24;
        float a[8] = {0,0,0,0,0,0,0,0};
        #pragma unroll
        for (int u = 0; u < 8; ++u) {
            const float wgt = s_cw[k*8+u];
            const short8v v = *(const short8v*)(smem + (sl + s_ci[k*8+u])*272 + cg*16);
            #pragma unroll
            for (int e = 0; e < 8; ++e) a[e] = fmaf(wgt, bf2f(v[e]), a[e]);
        }
        short8v o8;
        #pragma unroll
        for (int e = 0; e < 8; ++e) o8[e] = f2bf(a[e]);
        *(short8v*)(smem + FA_OFF + row*256 + ((cg*16) ^ ((row&7)<<4))) = o8;
    }
    __syncthreads();
    // phase G: gcn2 MFMA K=128 -> h2
    #pragma unroll
    for (int mi = 0; mi < 3; ++mi)
        #pragma unroll
        for (int ni = 0; ni < 2; ++ni) acc[mi][ni] = (f32x4){0.f,0.f,0.f,0.f};
    #pragma unroll
    for (int kc = 0; kc < 4; ++kc) {
        short8v bfr[2], afr[3];
        #pragma unroll
        for (int ni = 0; ni < 2; ++ni) {
            const int n = n0w + ni*16 + lr;
            bfr[ni] = *(const short8v*)(gw2b + (size_t)n*128 + kc*32 + lk*8);
        }
        #pragma unroll
        for (int mi = 0; mi < 3; ++mi) {
            const int row = m0w + mi*16 + lr;
            afr[mi] = *(const short8v*)(smem + FA_OFF + row*256 + ((kc*64 + lk*16) ^ ((row&7)<<4)));
        }
        #pragma unroll
        for (int mi = 0; mi < 3; ++mi)
            #pragma unroll
            for (int ni = 0; ni < 2; ++ni)
                acc[mi][ni] = __builtin_amdgcn_mfma_f32_16x16x32_bf16(afr[mi], bfr[ni], acc[mi][ni], 0, 0, 0);
    }
    #pragma unroll
    for (int ni = 0; ni < 2; ++ni) {
        const int o = n0w + ni*16 + lr;
        const float s = bn21[o] * rsqrtf(bn21[384 + o] + 1e-5f);
        const float t = bn21[128 + o] - bn21[256 + o]*s;
        const float g = s * gb2[o];
        #pragma unroll
        for (int mi = 0; mi < 3; ++mi)
            #pragma unroll
            for (int rg = 0; rg < 4; ++rg) {
                const int rl = m0w + mi*16 + lk*4 + rg;
                h2_out[(size_t)(r0 + rl)*128 + o] = f2bf(fmaxf(acc[mi][ni][rg] + t + g*s_cs[rl % 24], 0.f));
            }
    }
}

// ================================================================ KERNEL 2 (512 thr)
// stage h2 halo -> conv2 + f1 residual -> f2 (LDS + global) -> premix -> gcn3 -> h3
__global__ __launch_bounds__(512) void block2_kernel(
    const short* __restrict__ h2, const short* __restrict__ wt2b,
    const float* __restrict__ bn22, const float* __restrict__ tb2,
    const short* __restrict__ f1,
    const short* __restrict__ gw3b, const float* __restrict__ gb3, const float* __restrict__ bn31,
    const float* __restrict__ adjp,
    short* __restrict__ f2_out, short* __restrict__ h3_out)
{
    __shared__ char smem[LDS_SZ];
    float* s_cw  = (float*)(smem + TBL_OFF);
    int*   s_ci  = (int*)  (smem + TBL_OFF + 768);
    float* s_cs  = (float*)(smem + TBL_OFF + 1536);

    const int r0 = blockIdx.x * 96;
    const int bstart = (r0 / 6144) * 6144;
    const int bend = bstart + 6144;
    const int tid = threadIdx.x;
    const int l = tid & 63, wid = tid >> 6;
    const int m0w = (wid >> 2) * 48;
    const int lr = l & 15, lk = l >> 4;

    if (tid < 192) { s_cw[tid] = adjp[600 + tid]; s_ci[tid] = (int)adjp[792 + tid]; }
    else if (tid < 216) s_cs[tid - 192] = adjp[576 + (tid - 192)];
    // stage h2 halo 144x128 swizzled
    for (int ch = tid; ch < 144*16; ch += 512) {
        const int row = ch >> 4, cg = ch & 15;
        const int gr = r0 - 24 + row;
        float4 v = make_float4(0.f,0.f,0.f,0.f);
        if (gr >= bstart && gr < bend)
            v = *(const float4*)(h2 + (size_t)gr*128 + cg*8);
        *(float4*)(smem + row*256 + ((cg*16) ^ ((row&7)<<4))) = v;
    }
    __syncthreads();
    // conv2 MFMA (N=128, 4-way n split)
    {
        const int n0w = (wid & 3) * 32;
        f32x4 acc[3][2];
        #pragma unroll
        for (int mi = 0; mi < 3; ++mi)
            #pragma unroll
            for (int ni = 0; ni < 2; ++ni) acc[mi][ni] = (f32x4){0.f,0.f,0.f,0.f};
        #pragma unroll
        for (int dt = 0; dt < 3; ++dt) {
            #pragma unroll
            for (int kc = 0; kc < 4; ++kc) {
                short8v bfr[2], afr[3];
                #pragma unroll
                for (int ni = 0; ni < 2; ++ni) {
                    const int n = n0w + ni*16 + lr;
                    bfr[ni] = *(const short8v*)(wt2b + (size_t)n*384 + dt*128 + kc*32 + lk*8);
                }
                #pragma unroll
                for (int mi = 0; mi < 3; ++mi) {
                    const int row = m0w + dt*24 + mi*16 + lr;
                    afr[mi] = *(const short8v*)(smem + row*256 + ((kc*64 + lk*16) ^ ((row&7)<<4)));
                }
                #pragma unroll
                for (int mi = 0; mi < 3; ++mi)
                    #pragma unroll
                    for (int ni = 0; ni < 2; ++ni)
                        acc[mi][ni] = __builtin_amdgcn_mfma_f32_16x16x32_bf16(afr[mi], bfr[ni], acc[mi][ni], 0, 0, 0);
            }
        }
        __syncthreads();   // h2s dead
        // epilogue: + bias + f1 residual, relu -> f2raw LDS + f2 global
        #pragma unroll
        for (int ni = 0; ni < 2; ++ni) {
            const int o = n0w + ni*16 + lr;
            const float s = bn22[o] * rsqrtf(bn22[384 + o] + 1e-5f);
            const float bias = (bn22[128 + o] - bn22[256 + o]*s) + s*tb2[o];
            #pragma unroll
            for (int mi = 0; mi < 3; ++mi)
                #pragma unroll
                for (int rg = 0; rg < 4; ++rg) {
                    const int rl = m0w + mi*16 + lk*4 + rg;
                    const float res = bf2f(f1[(size_t)(r0 + rl)*128 + o]);
                    const short hv = f2bf(fmaxf(acc[mi][ni][rg] + bias + res, 0.f));
                    *(short*)(smem + rl*272 + o*2) = hv;
                    f2_out[(size_t)(r0 + rl)*128 + o] = hv;
                }
        }
    }
    __syncthreads();
    // premix f2 -> fa swizzled
    for (int task = tid; task < 96*16; task += 512) {
        const int row = task >> 4, cg = task & 15;
        const int k = row % 24, sl = (row / 24) * 24;
        float a[8] = {0,0,0,0,0,0,0,0};
        #pragma unroll
        for (int u = 0; u < 8; ++u) {
            const float wgt = s_cw[k*8+u];
            const short8v v = *(const short8v*)(smem + (sl + s_ci[k*8+u])*272 + cg*16);
            #pragma unroll
            for (int e = 0; e < 8; ++e) a[e] = fmaf(wgt, bf2f(v[e]), a[e]);
        }
        short8v o8;
        #pragma unroll
        for (int e = 0; e < 8; ++e) o8[e] = f2bf(a[e]);
        *(short8v*)(smem + FA_OFF + row*256 + ((cg*16) ^ ((row&7)<<4))) = o8;
    }
    __syncthreads();
    // gcn3 MFMA: K=128, N=256 (4-way n split, 64 cols each)
    {
        const int n0w = (wid & 3) * 64;
        f32x4 acc[3][4];
        #pragma unroll
        for (int mi = 0; mi < 3; ++mi)
            #pragma unroll
            for (int ni = 0; ni < 4; ++ni) acc[mi][ni] = (f32x4){0.f,0.f,0.f,0.f};
        #pragma unroll
        for (int kc = 0; kc < 4; ++kc) {
            short8v bfr[4], afr[3];
            #pragma unroll
            for (int ni = 0; ni < 4; ++ni) {
                const int n = n0w + ni*16 + lr;
                bfr[ni] = *(const short8v*)(gw3b + (size_t)n*128 + kc*32 + lk*8);
            }
            #pragma unroll
            for (int mi = 0; mi < 3; ++mi) {
                const int row = m0w + mi*16 + lr;
                afr[mi] = *(const short8v*)(smem + FA_OFF + row*256 + ((kc*64 + lk*16) ^ ((row&7)<<4)));
            }
            #pragma unroll
            for (int mi = 0; mi < 3; ++mi)
                #pragma unroll
                for (int ni = 0; ni < 4; ++ni)
                    acc[mi][ni] = __builtin_amdgcn_mfma_f32_16x16x32_bf16(afr[mi], bfr[ni], acc[mi][ni], 0, 0, 0);
        }
        #pragma unroll
        for (int ni = 0; ni < 4; ++ni) {
            const int o = n0w + ni*16 + lr;
            const float s = bn31[o] * rsqrtf(bn31[768 + o] + 1e-5f);
            const float t = bn31[256 + o] - bn31[512 + o]*s;
            const float g = s * gb3[o];
            #pragma unroll
            for (int mi = 0; mi < 3; ++mi)
                #pragma unroll
                for (int rg = 0; rg < 4; ++rg) {
                    const int rl = m0w + mi*16 + lk*4 + rg;
                    h3_out[(size_t)(r0 + rl)*256 + o] = f2bf(fmaxf(acc[mi][ni][rg] + t + g*s_cs[rl % 24], 0.f));
                }
        }
    }
}

// ================================================================ KERNEL 3 (512 thr)
// conv3 (K=768) + R3-on-the-fly (f2 @ rw3, K=128, accumulated into same acc) + BN + relu + pool
__global__ __launch_bounds__(512) void conv3_pool_kernel(
    const short* __restrict__ A, const short* __restrict__ Bw,
    const float* __restrict__ bn, const float* __restrict__ tb,
    const short* __restrict__ f2, const short* __restrict__ rw3b, const float* __restrict__ rb3,
    float* __restrict__ pooled)
{
    __shared__ short lds[176 * 128];
    const int r0 = blockIdx.x * 128, n0 = blockIdx.y * 128;
    const int bb = r0 / 6144;
    const int bstart = bb * 6144, bend = bstart + 6144;
    const int tid = threadIdx.x, l = tid & 63, wid = tid >> 6;
    const int m0w = (wid >> 2) * 64;          // 2-way M (64 rows, 4 frags)
    const int n0w = (wid & 3) * 32;           // 4-way N (32 cols, 2 frags)
    const int lr = l & 15, lk = l >> 4;

    f32x4 acc[4][2];
    #pragma unroll
    for (int mi = 0; mi < 4; ++mi)
        #pragma unroll
        for (int ni = 0; ni < 2; ++ni) acc[mi][ni] = (f32x4){0.f,0.f,0.f,0.f};

    for (int p = 0; p < 2; ++p) {
        if (p) __syncthreads();
        for (int ch = tid; ch < 176 * 16; ch += 512) {
            const int row = ch >> 4, c16 = ch & 15;
            const int gr = r0 - 24 + row;
            float4 v = make_float4(0.f,0.f,0.f,0.f);
            if (gr >= bstart && gr < bend)
                v = *(const float4*)(A + (size_t)gr * 256 + p * 128 + c16 * 8);
            *(float4*)((char*)lds + row * 256 + ((c16 * 16) ^ ((row & 7) << 4))) = v;
        }
        __syncthreads();
        #pragma unroll
        for (int dt = 0; dt < 3; ++dt) {
            #pragma unroll
            for (int kc = 0; kc < 4; ++kc) {
                short8v bfr[2], afr[4];
                #pragma unroll
                for (int ni = 0; ni < 2; ++ni) {
                    const int n = n0 + n0w + ni * 16 + lr;
                    bfr[ni] = *(const short8v*)(Bw + (size_t)n * 768 + dt * 256 + p * 128 + kc * 32 + lk * 8);
                }
                #pragma unroll
                for (int mi = 0; mi < 4; ++mi) {
                    const int row = m0w + dt * 24 + mi * 16 + lr;
                    afr[mi] = *(const short8v*)((char*)lds + row * 256 + ((kc * 64 + lk * 16) ^ ((row & 7) << 4)));
                }
                #pragma unroll
                for (int mi = 0; mi < 4; ++mi)
                    #pragma unroll
                    for (int ni = 0; ni < 2; ++ni)
                        acc[mi][ni] = __builtin_amdgcn_mfma_f32_16x16x32_bf16(afr[mi], bfr[ni], acc[mi][ni], 0, 0, 0);
            }
        }
    }
    // R3 GEMM: A-frags direct from global f2 (L2/L3-hot), accumulate into same acc
    #pragma unroll
    for (int kc = 0; kc < 4; ++kc) {
        short8v bfr[2], afr[4];
        #pragma unroll
        for (int ni = 0; ni < 2; ++ni) {
            const int n = n0 + n0w + ni * 16 + lr;
            bfr[ni] = *(const short8v*)(rw3b + (size_t)n * 128 + kc * 32 + lk * 8);
        }
        #pragma unroll
        for (int mi = 0; mi < 4; ++mi) {
            const int row = r0 + m0w + mi * 16 + lr;
            afr[mi] = *(const short8v*)(f2 + (size_t)row * 128 + kc * 32 + lk * 8);
        }
        #pragma unroll
        for (int mi = 0; mi < 4; ++mi)
            #pragma unroll
            for (int ni = 0; ni < 2; ++ni)
                acc[mi][ni] = __builtin_amdgcn_mfma_f32_16x16x32_bf16(afr[mi], bfr[ni], acc[mi][ni], 0, 0, 0);
    }

    float psum[2] = {0.f, 0.f};
    #pragma unroll
    for (int ni = 0; ni < 2; ++ni) {
        const int o = n0 + n0w + ni * 16 + lr;
        const float s = bn[o] * rsqrtf(bn[768 + o] + 1e-5f);
        const float t = bn[256 + o] - bn[512 + o] * s;
        const float bias = s * tb[o] + t + rb3[o];
        #pragma unroll
        for (int mi = 0; mi < 4; ++mi)
            #pragma unroll
            for (int rg = 0; rg < 4; ++rg)
                psum[ni] += fmaxf(acc[mi][ni][rg] + bias, 0.f);
    }
    #pragma unroll
    for (int ni = 0; ni < 2; ++ni) {
        float v = psum[ni];
        v += __shfl_xor(v, 16);
        v += __shfl_xor(v, 32);
        if (l < 16) atomicAdd(pooled + (size_t)bb * 256 + (n0 + n0w + ni * 16 + l), v);
    }
}

// ---------------------------------------------------------------- head
__global__ __launch_bounds__(256) void head_kernel(const float* __restrict__ pooled_sums,
    const float* __restrict__ ow, const float* __restrict__ ob, float* __restrict__ outp) {
    __shared__ float pooled[256];
    const int b = blockIdx.x, tid = threadIdx.x;
    pooled[tid] = pooled_sums[(size_t)b*256 + tid] * (1.f/6144.f);
    __syncthreads();
    for (int rep = 0; rep < 2; ++rep) {
        const int oo = rep*256 + tid;
        float a = ob[oo];
        const float4* wr = (const float4*)(ow + (size_t)oo*256);
        for (int c4 = 0; c4 < 64; ++c4) {
            const float4 w = wr[c4];
            const float4 p = *(const float4*)&pooled[c4*4];
            a += w.x*p.x + w.y*p.y + w.z*p.z + w.w*p.w;
        }
        outp[(size_t)b*512 + oo] = a;
    }
}

// ---------------------------------------------------------------- launch
extern "C" void kernel_launch(void* const* d_in, const int* in_sizes, int n_in,
                              void* d_out, int out_size, void* d_ws, size_t ws_size,
                              hipStream_t stream)
{
    const float* x        = (const float*)d_in[0];
    const float* b1_gcn_w = (const float*)d_in[1];
    const float* b1_gcn_b = (const float*)d_in[2];
    const float* b1_bn1   = (const float*)d_in[3];
    const float* b1_tcn_w = (const float*)d_in[4];
    const float* b1_tcn_b = (const float*)d_in[5];
    const float* b1_bn2   = (const float*)d_in[6];
    const float* b1_res_w = (const float*)d_in[7];
    const float* b1_res_b = (const float*)d_in[8];
    const float* b2_gcn_w = (const float*)d_in[9];
    const float* b2_gcn_b = (const float*)d_in[10];
    const float* b2_bn1   = (const float*)d_in[11];
    const float* b2_tcn_w = (const float*)d_in[12];
    const float* b2_tcn_b = (const float*)d_in[13];
    const float* b2_bn2   = (const float*)d_in[14];
    const float* b3_gcn_w = (const float*)d_in[15];
    const float* b3_gcn_b = (const float*)d_in[16];
    const float* b3_bn1   = (const float*)d_in[17];
    const float* b3_tcn_w = (const float*)d_in[18];
    const float* b3_tcn_b = (const float*)d_in[19];
    const float* b3_bn2   = (const float*)d_in[20];
    const float* b3_res_w = (const float*)d_in[21];
    const float* b3_res_b = (const float*)d_in[22];
    const float* out_w    = (const float*)d_in[23];
    const float* out_b    = (const float*)d_in[24];

    // ---- fixed workspace carve
    char* w = (char*)d_ws;
    float* adjp = (float*)w;   w += 4096;
    short* wt1b = (short*)w;   w += 98304;
    short* wt2b = (short*)w;   w += 98304;
    short* wt3b = (short*)w;   w += 393216;
    short* gw2b = (short*)w;   w += 32768;
    short* gw3b = (short*)w;   w += 65536;
    short* rw3b = (short*)w;   w += 65536;
    float* pooled = (float*)w; w += 32768;
    const size_t fixed = (size_t)(w - (char*)d_ws);

    // ---- adaptive batch-group: per-G bytes = 6144 * (256+256+256+512) = 7,864,320
    int G = 1;
    {
        const int tiers[6] = {32, 16, 8, 4, 2, 1};
        for (int ti = 0; ti < 6; ++ti) {
            const size_t need = fixed + (size_t)tiers[ti] * 7864320ull;
            if (need <= ws_size) { G = tiers[ti]; break; }
        }
    }
    const size_t MG = (size_t)G * 6144;

    short* f1 = (short*)w;           // MG*128
    short* h2 = f1 + MG*128;         // MG*128
    short* f2 = h2 + MG*128;         // MG*128
    short* h3 = f2 + MG*128;         // MG*256

    hipMemsetAsync(pooled, 0, 32*256*sizeof(float), stream);
    adj_init_kernel<<<1, 256, 0, stream>>>(adjp);
    prep_kernel<<<1472, 256, 0, stream>>>(b1_tcn_w, b1_bn2, b2_tcn_w, b2_bn2, b3_tcn_w, b3_bn2,
                                          b2_gcn_w, b2_bn1, b3_gcn_w, b3_bn1, b3_res_w,
                                          wt1b, wt2b, wt3b, gw2b, gw3b, rw3b);

    for (int b0 = 0; b0 < B_; b0 += G) {
        block1_kernel<<<64*G, 512, 0, stream>>>(
            x + (size_t)b0*6144*3,
            b1_gcn_w, b1_gcn_b, b1_bn1, b1_res_w, b1_res_b,
            b1_bn2, b1_tcn_b, wt1b,
            gw2b, b2_gcn_b, b2_bn1, adjp, f1, h2);
        block2_kernel<<<64*G, 512, 0, stream>>>(
            h2, wt2b, b2_bn2, b2_tcn_b, f1,
            gw3b, b3_gcn_b, b3_bn1, adjp, f2, h3);
        conv3_pool_kernel<<<dim3(48*G, 2), 512, 0, stream>>>(
            h3, wt3b, b3_bn2, b3_tcn_b, f2, rw3b, b3_res_b, pooled + (size_t)b0*256);
    }

    head_kernel<<<B_, 256, 0, stream>>>(pooled, out_w, out_b, (float*)d_out);
}

// Round 6
// 523.592 us; speedup vs baseline: 15.1120x; 1.0403x over previous
//
#include <hip/hip_runtime.h>
#include <math.h>

#define J_ 24
#define T_ 256
#define B_ 32

typedef short short8v __attribute__((ext_vector_type(8)));   // 8 x bf16 (4 VGPR)
typedef float f32x4  __attribute__((ext_vector_type(4)));    // MFMA acc

__device__ __forceinline__ short f2bf(float f) {
    unsigned u = __float_as_uint(f);
    u += 0x7fffu + ((u >> 16) & 1u);          // round-to-nearest-even
    return (short)(u >> 16);
}
__device__ __forceinline__ float bf2f(short s) {
    return __uint_as_float(((unsigned)(unsigned short)s) << 16);
}

__device__ __constant__ int d_parent[24] = {-1,0,0,0,1,2,3,4,5,6,7,8,9,9,9,12,13,14,16,17,18,19,20,21};

// ---------------------------------------------------------------- adjacency tables
// adjp[0..575] dense ADJ ; [576..599] colsum ; [600..791] CSR wgt (24x8) ; [792..983] CSR idx
__global__ void adj_init_kernel(float* __restrict__ adj_out) {
    __shared__ float s_adj[576];
    const int tid = threadIdx.x;
    for (int i = tid; i < 576; i += 256) {
        const int j = i / 24, k = i % 24;
        float a = (j == k || d_parent[k] == j || d_parent[j] == k) ? 1.f : 0.f;
        float d = 0.f;
        for (int kk = 0; kk < 24; ++kk)
            d += (j == kk || d_parent[kk] == j || d_parent[j] == kk) ? 1.f : 0.f;
        const float v = a / fmaxf(d, 1.f);
        s_adj[i] = v;
        adj_out[i] = v;
    }
    __syncthreads();
    if (tid < 24) {
        float cs = 0.f;
        for (int j = 0; j < 24; ++j) cs += s_adj[j*24 + tid];
        adj_out[576 + tid] = cs;
        int n = 0;
        for (int j = 0; j < 24; ++j) {
            const float w = s_adj[j*24 + tid];
            if (w != 0.f && n < 8) {
                adj_out[600 + tid*8 + n] = w;
                adj_out[792 + tid*8 + n] = (float)j;
                ++n;
            }
        }
        for (; n < 8; ++n) { adj_out[600 + tid*8 + n] = 0.f; adj_out[792 + tid*8 + n] = 0.f; }
    }
}

// ---------------------------------------------------------------- fused weight prep
__global__ __launch_bounds__(256) void prep_kernel(
    const float* __restrict__ w1t, const float* __restrict__ bn1_2,
    const float* __restrict__ w2t, const float* __restrict__ bn2_2,
    const float* __restrict__ w3t, const float* __restrict__ bn3_2,
    const float* __restrict__ g2w, const float* __restrict__ bn2_1,
    const float* __restrict__ g3w, const float* __restrict__ bn3_1,
    const float* __restrict__ r3w,
    short* __restrict__ wt1b, short* __restrict__ wt2b, short* __restrict__ wt3b,
    short* __restrict__ gw2b, short* __restrict__ gw3b, short* __restrict__ rw3b)
{
    const int i = blockIdx.x * 256 + threadIdx.x;
    if (i < 49152) {
        const int o = i / 384, r = i % 384, dt = r / 128, c = r % 128;
        const float s = bn1_2[o] * rsqrtf(bn1_2[384 + o] + 1e-5f);
        wt1b[i] = f2bf(s * w1t[(o*128 + c)*3 + dt]);
    } else if (i < 98304) {
        const int j = i - 49152;
        const int o = j / 384, r = j % 384, dt = r / 128, c = r % 128;
        const float s = bn2_2[o] * rsqrtf(bn2_2[384 + o] + 1e-5f);
        wt2b[j] = f2bf(s * w2t[(o*128 + c)*3 + dt]);
    } else if (i < 294912) {
        const int j = i - 98304;
        const int o = j / 768, r = j % 768, dt = r / 256, c = r % 256;
        const float s = bn3_2[o] * rsqrtf(bn3_2[768 + o] + 1e-5f);
        wt3b[j] = f2bf(s * w3t[(o*256 + c)*3 + dt]);
    } else if (i < 311296) {
        const int j = i - 294912;
        const int o = j / 128;
        const float s = bn2_1[o] * rsqrtf(bn2_1[384 + o] + 1e-5f);
        gw2b[j] = f2bf(s * g2w[j]);
    } else if (i < 344064) {
        const int j = i - 311296;
        const int o = j / 128;
        const float s = bn3_1[o] * rsqrtf(bn3_1[768 + o] + 1e-5f);
        gw3b[j] = f2bf(s * g3w[j]);
    } else if (i < 376832) {
        const int j = i - 344064;
        rw3b[j] = f2bf(r3w[j]);
    }
}

// LDS layout (block1/block2), 52,320 B -> 3 blocks/CU
#define LDS_SZ   52320
#define FA_OFF   26112
#define X6_OFF   40320
#define XA6_OFF  44176
#define TBL_OFF  50688

// ================================================================ KERNEL 1 (512 thr)
__global__ __launch_bounds__(512) void block1_kernel(
    const float* __restrict__ x,
    const float* __restrict__ gw1, const float* __restrict__ gb1, const float* __restrict__ bn1,
    const float* __restrict__ rw1, const float* __restrict__ rb1,
    const float* __restrict__ bn12, const float* __restrict__ tb1, const short* __restrict__ wt1b,
    const short* __restrict__ gw2b, const float* __restrict__ gb2, const float* __restrict__ bn21,
    const float* __restrict__ adjp,
    short* __restrict__ f1_out, short* __restrict__ h2_out)
{
    __shared__ char smem[LDS_SZ];
    float* s_x6  = (float*)(smem + X6_OFF);
    float* s_xa6 = (float*)(smem + XA6_OFF);
    float* s_cw  = (float*)(smem + TBL_OFF);
    int*   s_ci  = (int*)  (smem + TBL_OFF + 768);
    float* s_cs  = (float*)(smem + TBL_OFF + 1536);

    const int r0 = blockIdx.x * 96;
    const int bstart = (r0 / 6144) * 6144;
    const int bend = bstart + 6144;
    const int tid = threadIdx.x;
    const int l = tid & 63, wid = tid >> 6;
    const int m0w = (wid >> 2) * 48;
    const int n0w = (wid & 3) * 32;
    const int lr = l & 15, lk = l >> 4;

    if (tid < 192) { s_cw[tid] = adjp[600 + tid]; s_ci[tid] = (int)adjp[792 + tid]; }
    else if (tid < 216) s_cs[tid - 192] = adjp[576 + (tid - 192)];
    if (tid < 144) {
        const int gr = r0 - 24 + tid;
        float o0=0,o1=0,o2=0,o3=0,o4=0,o5=0;
        if (gr >= bstart && gr < bend) {
            const float ax = x[gr*3+0], ay = x[gr*3+1], az = x[gr*3+2];
            const float angle = sqrtf(ax*ax + ay*ay + az*az);
            const float inv = 1.f / (angle + 1e-8f);
            const float ux = ax*inv, uy = ay*inv, uz = az*inv;
            const float c = cosf(angle), s = sinf(angle), omc = 1.f - c;
            o0 = c + omc*ux*ux;   o1 = omc*ux*uy - s*uz;
            o2 = omc*uy*ux + s*uz; o3 = c + omc*uy*uy;
            o4 = omc*uz*ux - s*uy; o5 = omc*uz*uy + s*ux;
        }
        float* p = s_x6 + tid*6;
        p[0]=o0; p[1]=o1; p[2]=o2; p[3]=o3; p[4]=o4; p[5]=o5;
    }
    __syncthreads();
    for (int idx = tid; idx < 864; idx += 512) {
        const int hr = idx / 6, c = idx % 6;
        const int k = hr % 24, sl = (hr / 24) * 24;
        float a = 0.f;
        #pragma unroll
        for (int u = 0; u < 8; ++u)
            a = fmaf(s_cw[k*8+u], s_x6[(sl + s_ci[k*8+u])*6 + c], a);
        s_xa6[hr*6 + c] = a;
    }
    __syncthreads();
    {
        const int o = tid & 127, q = tid >> 7;
        const float s1 = bn1[o] * rsqrtf(bn1[384 + o] + 1e-5f);
        const float t1 = bn1[128 + o] - bn1[256 + o] * s1;
        const float g1 = s1 * gb1[o];
        float wg[6];
        #pragma unroll
        for (int c = 0; c < 6; ++c) wg[c] = gw1[o*6 + c];
        for (int hr = q; hr < 144; hr += 4) {
            const int gr = r0 - 24 + hr;
            short hv = 0;
            if (gr >= bstart && gr < bend) {
                float a = 0.f;
                #pragma unroll
                for (int c = 0; c < 6; ++c) a = fmaf(s_xa6[hr*6 + c], wg[c], a);
                hv = f2bf(fmaxf(s1*a + t1 + g1*s_cs[hr % 24], 0.f));
            }
            *(short*)(smem + hr*256 + ((((o*2)&0xF0)) ^ ((hr&7)<<4)) + ((o*2)&14)) = hv;
        }
    }
    __syncthreads();
    f32x4 acc[3][2];
    #pragma unroll
    for (int mi = 0; mi < 3; ++mi)
        #pragma unroll
        for (int ni = 0; ni < 2; ++ni) acc[mi][ni] = (f32x4){0.f,0.f,0.f,0.f};
    #pragma unroll
    for (int dt = 0; dt < 3; ++dt) {
        #pragma unroll
        for (int kc = 0; kc < 4; ++kc) {
            short8v bfr[2], afr[3];
            #pragma unroll
            for (int ni = 0; ni < 2; ++ni) {
                const int n = n0w + ni*16 + lr;
                bfr[ni] = *(const short8v*)(wt1b + (size_t)n*384 + dt*128 + kc*32 + lk*8);
            }
            #pragma unroll
            for (int mi = 0; mi < 3; ++mi) {
                const int row = m0w + dt*24 + mi*16 + lr;
                afr[mi] = *(const short8v*)(smem + row*256 + ((kc*64 + lk*16) ^ ((row&7)<<4)));
            }
            #pragma unroll
            for (int mi = 0; mi < 3; ++mi)
                #pragma unroll
                for (int ni = 0; ni < 2; ++ni)
                    acc[mi][ni] = __builtin_amdgcn_mfma_f32_16x16x32_bf16(afr[mi], bfr[ni], acc[mi][ni], 0, 0, 0);
        }
    }
    __syncthreads();
    #pragma unroll
    for (int ni = 0; ni < 2; ++ni) {
        const int o = n0w + ni*16 + lr;
        const float s2 = bn12[o] * rsqrtf(bn12[384 + o] + 1e-5f);
        const float bias = (bn12[128 + o] - bn12[256 + o]*s2) + s2*tb1[o];
        float wr[6];
        #pragma unroll
        for (int c = 0; c < 6; ++c) wr[c] = rw1[o*6 + c];
        const float rb = rb1[o];
        #pragma unroll
        for (int mi = 0; mi < 3; ++mi)
            #pragma unroll
            for (int rg = 0; rg < 4; ++rg) {
                const int rl = m0w + mi*16 + lk*4 + rg;
                float r = rb;
                #pragma unroll
                for (int c = 0; c < 6; ++c) r = fmaf(s_x6[(rl+24)*6 + c], wr[c], r);
                const short hv = f2bf(fmaxf(acc[mi][ni][rg] + bias + r, 0.f));
                f1_out[(size_t)(r0 + rl)*128 + o] = hv;
                *(short*)(smem + rl*272 + o*2) = hv;
            }
    }
    __syncthreads();
    for (int task = tid; task < 96*16; task += 512) {
        const int row = task >> 4, cg = task & 15;
        const int k = row % 24, sl = (row / 24) * 24;
        float a[8] = {0,0,0,0,0,0,0,0};
        #pragma unroll
        for (int u = 0; u < 8; ++u) {
            const float wgt = s_cw[k*8+u];
            const short8v v = *(const short8v*)(smem + (sl + s_ci[k*8+u])*272 + cg*16);
            #pragma unroll
            for (int e = 0; e < 8; ++e) a[e] = fmaf(wgt, bf2f(v[e]), a[e]);
        }
        short8v o8;
        #pragma unroll
        for (int e = 0; e < 8; ++e) o8[e] = f2bf(a[e]);
        *(short8v*)(smem + FA_OFF + row*256 + ((cg*16) ^ ((row&7)<<4))) = o8;
    }
    __syncthreads();
    #pragma unroll
    for (int mi = 0; mi < 3; ++mi)
        #pragma unroll
        for (int ni = 0; ni < 2; ++ni) acc[mi][ni] = (f32x4){0.f,0.f,0.f,0.f};
    #pragma unroll
    for (int kc = 0; kc < 4; ++kc) {
        short8v bfr[2], afr[3];
        #pragma unroll
        for (int ni = 0; ni < 2; ++ni) {
            const int n = n0w + ni*16 + lr;
            bfr[ni] = *(const short8v*)(gw2b + (size_t)n*128 + kc*32 + lk*8);
        }
        #pragma unroll
        for (int mi = 0; mi < 3; ++mi) {
            const int row = m0w + mi*16 + lr;
            afr[mi] = *(const short8v*)(smem + FA_OFF + row*256 + ((kc*64 + lk*16) ^ ((row&7)<<4)));
        }
        #pragma unroll
        for (int mi = 0; mi < 3; ++mi)
            #pragma unroll
            for (int ni = 0; ni < 2; ++ni)
                acc[mi][ni] = __builtin_amdgcn_mfma_f32_16x16x32_bf16(afr[mi], bfr[ni], acc[mi][ni], 0, 0, 0);
    }
    #pragma unroll
    for (int ni = 0; ni < 2; ++ni) {
        const int o = n0w + ni*16 + lr;
        const float s = bn21[o] * rsqrtf(bn21[384 + o] + 1e-5f);
        const float t = bn21[128 + o] - bn21[256 + o]*s;
        const float g = s * gb2[o];
        #pragma unroll
        for (int mi = 0; mi < 3; ++mi)
            #pragma unroll
            for (int rg = 0; rg < 4; ++rg) {
                const int rl = m0w + mi*16 + lk*4 + rg;
                h2_out[(size_t)(r0 + rl)*128 + o] = f2bf(fmaxf(acc[mi][ni][rg] + t + g*s_cs[rl % 24], 0.f));
            }
    }
}

// ================================================================ KERNEL 2 (512 thr)
__global__ __launch_bounds__(512) void block2_kernel(
    const short* __restrict__ h2, const short* __restrict__ wt2b,
    const float* __restrict__ bn22, const float* __restrict__ tb2,
    const short* __restrict__ f1,
    const short* __restrict__ gw3b, const float* __restrict__ gb3, const float* __restrict__ bn31,
    const float* __restrict__ adjp,
    short* __restrict__ f2_out, short* __restrict__ h3_out)
{
    __shared__ char smem[LDS_SZ];
    float* s_cw  = (float*)(smem + TBL_OFF);
    int*   s_ci  = (int*)  (smem + TBL_OFF + 768);
    float* s_cs  = (float*)(smem + TBL_OFF + 1536);

    const int r0 = blockIdx.x * 96;
    const int bstart = (r0 / 6144) * 6144;
    const int bend = bstart + 6144;
    const int tid = threadIdx.x;
    const int l = tid & 63, wid = tid >> 6;
    const int m0w = (wid >> 2) * 48;
    const int lr = l & 15, lk = l >> 4;

    if (tid < 192) { s_cw[tid] = adjp[600 + tid]; s_ci[tid] = (int)adjp[792 + tid]; }
    else if (tid < 216) s_cs[tid - 192] = adjp[576 + (tid - 192)];
    for (int ch = tid; ch < 144*16; ch += 512) {
        const int row = ch >> 4, cg = ch & 15;
        const int gr = r0 - 24 + row;
        float4 v = make_float4(0.f,0.f,0.f,0.f);
        if (gr >= bstart && gr < bend)
            v = *(const float4*)(h2 + (size_t)gr*128 + cg*8);
        *(float4*)(smem + row*256 + ((cg*16) ^ ((row&7)<<4))) = v;
    }
    __syncthreads();
    {
        const int n0w = (wid & 3) * 32;
        f32x4 acc[3][2];
        #pragma unroll
        for (int mi = 0; mi < 3; ++mi)
            #pragma unroll
            for (int ni = 0; ni < 2; ++ni) acc[mi][ni] = (f32x4){0.f,0.f,0.f,0.f};
        #pragma unroll
        for (int dt = 0; dt < 3; ++dt) {
            #pragma unroll
            for (int kc = 0; kc < 4; ++kc) {
                short8v bfr[2], afr[3];
                #pragma unroll
                for (int ni = 0; ni < 2; ++ni) {
                    const int n = n0w + ni*16 + lr;
                    bfr[ni] = *(const short8v*)(wt2b + (size_t)n*384 + dt*128 + kc*32 + lk*8);
                }
                #pragma unroll
                for (int mi = 0; mi < 3; ++mi) {
                    const int row = m0w + dt*24 + mi*16 + lr;
                    afr[mi] = *(const short8v*)(smem + row*256 + ((kc*64 + lk*16) ^ ((row&7)<<4)));
                }
                #pragma unroll
                for (int mi = 0; mi < 3; ++mi)
                    #pragma unroll
                    for (int ni = 0; ni < 2; ++ni)
                        acc[mi][ni] = __builtin_amdgcn_mfma_f32_16x16x32_bf16(afr[mi], bfr[ni], acc[mi][ni], 0, 0, 0);
            }
        }
        __syncthreads();
        #pragma unroll
        for (int ni = 0; ni < 2; ++ni) {
            const int o = n0w + ni*16 + lr;
            const float s = bn22[o] * rsqrtf(bn22[384 + o] + 1e-5f);
            const float bias = (bn22[128 + o] - bn22[256 + o]*s) + s*tb2[o];
            #pragma unroll
            for (int mi = 0; mi < 3; ++mi)
                #pragma unroll
                for (int rg = 0; rg < 4; ++rg) {
                    const int rl = m0w + mi*16 + lk*4 + rg;
                    const float res = bf2f(f1[(size_t)(r0 + rl)*128 + o]);
                    const short hv = f2bf(fmaxf(acc[mi][ni][rg] + bias + res, 0.f));
                    *(short*)(smem + rl*272 + o*2) = hv;
                    f2_out[(size_t)(r0 + rl)*128 + o] = hv;
                }
        }
    }
    __syncthreads();
    for (int task = tid; task < 96*16; task += 512) {
        const int row = task >> 4, cg = task & 15;
        const int k = row % 24, sl = (row / 24) * 24;
        float a[8] = {0,0,0,0,0,0,0,0};
        #pragma unroll
        for (int u = 0; u < 8; ++u) {
            const float wgt = s_cw[k*8+u];
            const short8v v = *(const short8v*)(smem + (sl + s_ci[k*8+u])*272 + cg*16);
            #pragma unroll
            for (int e = 0; e < 8; ++e) a[e] = fmaf(wgt, bf2f(v[e]), a[e]);
        }
        short8v o8;
        #pragma unroll
        for (int e = 0; e < 8; ++e) o8[e] = f2bf(a[e]);
        *(short8v*)(smem + FA_OFF + row*256 + ((cg*16) ^ ((row&7)<<4))) = o8;
    }
    __syncthreads();
    {
        const int n0w = (wid & 3) * 64;
        f32x4 acc[3][4];
        #pragma unroll
        for (int mi = 0; mi < 3; ++mi)
            #pragma unroll
            for (int ni = 0; ni < 4; ++ni) acc[mi][ni] = (f32x4){0.f,0.f,0.f,0.f};
        #pragma unroll
        for (int kc = 0; kc < 4; ++kc) {
            short8v bfr[4], afr[3];
            #pragma unroll
            for (int ni = 0; ni < 4; ++ni) {
                const int n = n0w + ni*16 + lr;
                bfr[ni] = *(const short8v*)(gw3b + (size_t)n*128 + kc*32 + lk*8);
            }
            #pragma unroll
            for (int mi = 0; mi < 3; ++mi) {
                const int row = m0w + mi*16 + lr;
                afr[mi] = *(const short8v*)(smem + FA_OFF + row*256 + ((kc*64 + lk*16) ^ ((row&7)<<4)));
            }
            #pragma unroll
            for (int mi = 0; mi < 3; ++mi)
                #pragma unroll
                for (int ni = 0; ni < 4; ++ni)
                    acc[mi][ni] = __builtin_amdgcn_mfma_f32_16x16x32_bf16(afr[mi], bfr[ni], acc[mi][ni], 0, 0, 0);
        }
        #pragma unroll
        for (int ni = 0; ni < 4; ++ni) {
            const int o = n0w + ni*16 + lr;
            const float s = bn31[o] * rsqrtf(bn31[768 + o] + 1e-5f);
            const float t = bn31[256 + o] - bn31[512 + o]*s;
            const float g = s * gb3[o];
            #pragma unroll
            for (int mi = 0; mi < 3; ++mi)
                #pragma unroll
                for (int rg = 0; rg < 4; ++rg) {
                    const int rl = m0w + mi*16 + lk*4 + rg;
                    h3_out[(size_t)(r0 + rl)*256 + o] = f2bf(fmaxf(acc[mi][ni][rg] + t + g*s_cs[rl % 24], 0.f));
                }
        }
    }
}

// ================================================================ KERNEL 3 (512 thr, full N=256)
// conv3 (K=768) over h3 + R3 (f2 @ rw3, K=128, f2 staged via LDS) + BN + relu + pool
__global__ __launch_bounds__(512, 4) void conv3_pool_kernel(
    const short* __restrict__ A, const short* __restrict__ Bw,
    const float* __restrict__ bn, const float* __restrict__ tb,
    const short* __restrict__ f2, const short* __restrict__ rw3b, const float* __restrict__ rb3,
    float* __restrict__ pooled)
{
    __shared__ short lds[176 * 128];
    const int r0 = blockIdx.x * 128;
    const int bb = r0 / 6144;
    const int bstart = bb * 6144, bend = bstart + 6144;
    const int tid = threadIdx.x, l = tid & 63, wid = tid >> 6;
    const int m0w = (wid >> 2) * 64;          // 2-way M (64 rows, 4 frags)
    const int n0w = (wid & 3) * 64;           // 4-way N (64 cols, 4 frags)
    const int lr = l & 15, lk = l >> 4;

    f32x4 acc[4][4];
    #pragma unroll
    for (int mi = 0; mi < 4; ++mi)
        #pragma unroll
        for (int ni = 0; ni < 4; ++ni) acc[mi][ni] = (f32x4){0.f,0.f,0.f,0.f};

    for (int p = 0; p < 2; ++p) {
        if (p) __syncthreads();
        for (int ch = tid; ch < 176 * 16; ch += 512) {
            const int row = ch >> 4, c16 = ch & 15;
            const int gr = r0 - 24 + row;
            float4 v = make_float4(0.f,0.f,0.f,0.f);
            if (gr >= bstart && gr < bend)
                v = *(const float4*)(A + (size_t)gr * 256 + p * 128 + c16 * 8);
            *(float4*)((char*)lds + row * 256 + ((c16 * 16) ^ ((row & 7) << 4))) = v;
        }
        __syncthreads();
        #pragma unroll
        for (int dt = 0; dt < 3; ++dt) {
            #pragma unroll
            for (int kc = 0; kc < 4; ++kc) {
                short8v bfr[4], afr[4];
                #pragma unroll
                for (int ni = 0; ni < 4; ++ni) {
                    const int n = n0w + ni * 16 + lr;
                    bfr[ni] = *(const short8v*)(Bw + (size_t)n * 768 + dt * 256 + p * 128 + kc * 32 + lk * 8);
                }
                #pragma unroll
                for (int mi = 0; mi < 4; ++mi) {
                    const int row = m0w + dt * 24 + mi * 16 + lr;
                    afr[mi] = *(const short8v*)((char*)lds + row * 256 + ((kc * 64 + lk * 16) ^ ((row & 7) << 4)));
                }
                #pragma unroll
                for (int mi = 0; mi < 4; ++mi)
                    #pragma unroll
                    for (int ni = 0; ni < 4; ++ni)
                        acc[mi][ni] = __builtin_amdgcn_mfma_f32_16x16x32_bf16(afr[mi], bfr[ni], acc[mi][ni], 0, 0, 0);
            }
        }
    }
    // stage f2 tile (128 x 128ch) into LDS coalesced, then R3 MFMA from LDS
    __syncthreads();
    for (int ch = tid; ch < 128 * 16; ch += 512) {
        const int row = ch >> 4, c16 = ch & 15;
        const float4 v = *(const float4*)(f2 + (size_t)(r0 + row) * 128 + c16 * 8);
        *(float4*)((char*)lds + row * 256 + ((c16 * 16) ^ ((row & 7) << 4))) = v;
    }
    __syncthreads();
    #pragma unroll
    for (int kc = 0; kc < 4; ++kc) {
        short8v bfr[4], afr[4];
        #pragma unroll
        for (int ni = 0; ni < 4; ++ni) {
            const int n = n0w + ni * 16 + lr;
            bfr[ni] = *(const short8v*)(rw3b + (size_t)n * 128 + kc * 32 + lk * 8);
        }
        #pragma unroll
        for (int mi = 0; mi < 4; ++mi) {
            const int row = m0w + mi * 16 + lr;
            afr[mi] = *(const short8v*)((char*)lds + row * 256 + ((kc * 64 + lk * 16) ^ ((row & 7) << 4)));
        }
        #pragma unroll
        for (int mi = 0; mi < 4; ++mi)
            #pragma unroll
            for (int ni = 0; ni < 4; ++ni)
                acc[mi][ni] = __builtin_amdgcn_mfma_f32_16x16x32_bf16(afr[mi], bfr[ni], acc[mi][ni], 0, 0, 0);
    }

    float psum[4] = {0.f, 0.f, 0.f, 0.f};
    #pragma unroll
    for (int ni = 0; ni < 4; ++ni) {
        const int o = n0w + ni * 16 + lr;
        const float s = bn[o] * rsqrtf(bn[768 + o] + 1e-5f);
        const float t = bn[256 + o] - bn[512 + o] * s;
        const float bias = s * tb[o] + t + rb3[o];
        #pragma unroll
        for (int mi = 0; mi < 4; ++mi)
            #pragma unroll
            for (int rg = 0; rg < 4; ++rg)
                psum[ni] += fmaxf(acc[mi][ni][rg] + bias, 0.f);
    }
    #pragma unroll
    for (int ni = 0; ni < 4; ++ni) {
        float v = psum[ni];
        v += __shfl_xor(v, 16);
        v += __shfl_xor(v, 32);
        if (l < 16) atomicAdd(pooled + (size_t)bb * 256 + (n0w + ni * 16 + l), v);
    }
}

// ---------------------------------------------------------------- head
__global__ __launch_bounds__(256) void head_kernel(const float* __restrict__ pooled_sums,
    const float* __restrict__ ow, const float* __restrict__ ob, float* __restrict__ outp) {
    __shared__ float pooled[256];
    const int b = blockIdx.x, tid = threadIdx.x;
    pooled[tid] = pooled_sums[(size_t)b*256 + tid] * (1.f/6144.f);
    __syncthreads();
    for (int rep = 0; rep < 2; ++rep) {
        const int oo = rep*256 + tid;
        float a = ob[oo];
        const float4* wr = (const float4*)(ow + (size_t)oo*256);
        for (int c4 = 0; c4 < 64; ++c4) {
            const float4 w = wr[c4];
            const float4 p = *(const float4*)&pooled[c4*4];
            a += w.x*p.x + w.y*p.y + w.z*p.z + w.w*p.w;
        }
        outp[(size_t)b*512 + oo] = a;
    }
}

// ---------------------------------------------------------------- launch
extern "C" void kernel_launch(void* const* d_in, const int* in_sizes, int n_in,
                              void* d_out, int out_size, void* d_ws, size_t ws_size,
                              hipStream_t stream)
{
    const float* x        = (const float*)d_in[0];
    const float* b1_gcn_w = (const float*)d_in[1];
    const float* b1_gcn_b = (const float*)d_in[2];
    const float* b1_bn1   = (const float*)d_in[3];
    const float* b1_tcn_w = (const float*)d_in[4];
    const float* b1_tcn_b = (const float*)d_in[5];
    const float* b1_bn2   = (const float*)d_in[6];
    const float* b1_res_w = (const float*)d_in[7];
    const float* b1_res_b = (const float*)d_in[8];
    const float* b2_gcn_w = (const float*)d_in[9];
    const float* b2_gcn_b = (const float*)d_in[10];
    const float* b2_bn1   = (const float*)d_in[11];
    const float* b2_tcn_w = (const float*)d_in[12];
    const float* b2_tcn_b = (const float*)d_in[13];
    const float* b2_bn2   = (const float*)d_in[14];
    const float* b3_gcn_w = (const float*)d_in[15];
    const float* b3_gcn_b = (const float*)d_in[16];
    const float* b3_bn1   = (const float*)d_in[17];
    const float* b3_tcn_w = (const float*)d_in[18];
    const float* b3_tcn_b = (const float*)d_in[19];
    const float* b3_bn2   = (const float*)d_in[20];
    const float* b3_res_w = (const float*)d_in[21];
    const float* b3_res_b = (const float*)d_in[22];
    const float* out_w    = (const float*)d_in[23];
    const float* out_b    = (const float*)d_in[24];

    // ---- fixed workspace carve
    char* w = (char*)d_ws;
    float* adjp = (float*)w;   w += 4096;
    short* wt1b = (short*)w;   w += 98304;
    short* wt2b = (short*)w;   w += 98304;
    short* wt3b = (short*)w;   w += 393216;
    short* gw2b = (short*)w;   w += 32768;
    short* gw3b = (short*)w;   w += 65536;
    short* rw3b = (short*)w;   w += 65536;
    float* pooled = (float*)w; w += 32768;
    const size_t fixed = (size_t)(w - (char*)d_ws);

    // ---- adaptive batch-group: per-G bytes = 6144 * (256+256+512) = 6,291,456
    //      (f2 aliases f1: block2 reads f1[row] then writes f2[row] in the same thread)
    int G = 1;
    {
        const int tiers[6] = {32, 16, 8, 4, 2, 1};
        for (int ti = 0; ti < 6; ++ti) {
            const size_t need = fixed + (size_t)tiers[ti] * 6291456ull;
            if (need <= ws_size) { G = tiers[ti]; break; }
        }
    }
    const size_t MG = (size_t)G * 6144;

    short* f1 = (short*)w;           // MG*128  (also serves as f2 after block2)
    short* h2 = f1 + MG*128;         // MG*128
    short* h3 = h2 + MG*128;         // MG*256
    short* f2 = f1;                  // alias

    hipMemsetAsync(pooled, 0, 32*256*sizeof(float), stream);
    adj_init_kernel<<<1, 256, 0, stream>>>(adjp);
    prep_kernel<<<1472, 256, 0, stream>>>(b1_tcn_w, b1_bn2, b2_tcn_w, b2_bn2, b3_tcn_w, b3_bn2,
                                          b2_gcn_w, b2_bn1, b3_gcn_w, b3_bn1, b3_res_w,
                                          wt1b, wt2b, wt3b, gw2b, gw3b, rw3b);

    for (int b0 = 0; b0 < B_; b0 += G) {
        block1_kernel<<<64*G, 512, 0, stream>>>(
            x + (size_t)b0*6144*3,
            b1_gcn_w, b1_gcn_b, b1_bn1, b1_res_w, b1_res_b,
            b1_bn2, b1_tcn_b, wt1b,
            gw2b, b2_gcn_b, b2_bn1, adjp, f1, h2);
        block2_kernel<<<64*G, 512, 0, stream>>>(
            h2, wt2b, b2_bn2, b2_tcn_b, f1,
            gw3b, b3_gcn_b, b3_bn1, adjp, f2, h3);
        conv3_pool_kernel<<<48*G, 512, 0, stream>>>(
            h3, wt3b, b3_bn2, b3_tcn_b, f2, rw3b, b3_res_b, pooled + (size_t)b0*256);
    }

    head_kernel<<<B_, 256, 0, stream>>>(pooled, out_w, out_b, (float*)d_out);
}

// Round 7
// 473.569 us; speedup vs baseline: 16.7083x; 1.1056x over previous
//
#include <hip/hip_runtime.h>
#include <math.h>

#define J_ 24
#define T_ 256
#define B_ 32

typedef short short8v __attribute__((ext_vector_type(8)));   // 8 x bf16 (4 VGPR)
typedef float f32x4  __attribute__((ext_vector_type(4)));    // MFMA acc

__device__ __forceinline__ short f2bf(float f) {
    unsigned u = __float_as_uint(f);
    u += 0x7fffu + ((u >> 16) & 1u);          // round-to-nearest-even
    return (short)(u >> 16);
}
__device__ __forceinline__ float bf2f(short s) {
    return __uint_as_float(((unsigned)(unsigned short)s) << 16);
}

__device__ __constant__ int d_parent[24] = {-1,0,0,0,1,2,3,4,5,6,7,8,9,9,9,12,13,14,16,17,18,19,20,21};

// ---------------------------------------------------------------- adjacency tables
// adjp[0..575] dense ADJ ; [576..599] colsum ; [600..791] CSR wgt (24x8) ; [792..983] CSR idx
__global__ void adj_init_kernel(float* __restrict__ adj_out) {
    __shared__ float s_adj[576];
    const int tid = threadIdx.x;
    for (int i = tid; i < 576; i += 256) {
        const int j = i / 24, k = i % 24;
        float a = (j == k || d_parent[k] == j || d_parent[j] == k) ? 1.f : 0.f;
        float d = 0.f;
        for (int kk = 0; kk < 24; ++kk)
            d += (j == kk || d_parent[kk] == j || d_parent[j] == kk) ? 1.f : 0.f;
        const float v = a / fmaxf(d, 1.f);
        s_adj[i] = v;
        adj_out[i] = v;
    }
    __syncthreads();
    if (tid < 24) {
        float cs = 0.f;
        for (int j = 0; j < 24; ++j) cs += s_adj[j*24 + tid];
        adj_out[576 + tid] = cs;
        int n = 0;
        for (int j = 0; j < 24; ++j) {
            const float w = s_adj[j*24 + tid];
            if (w != 0.f && n < 8) {
                adj_out[600 + tid*8 + n] = w;
                adj_out[792 + tid*8 + n] = (float)j;
                ++n;
            }
        }
        for (; n < 8; ++n) { adj_out[600 + tid*8 + n] = 0.f; adj_out[792 + tid*8 + n] = 0.f; }
    }
}

// ---------------------------------------------------------------- fused weight prep
__global__ __launch_bounds__(256) void prep_kernel(
    const float* __restrict__ w1t, const float* __restrict__ bn1_2,
    const float* __restrict__ w2t, const float* __restrict__ bn2_2,
    const float* __restrict__ w3t, const float* __restrict__ bn3_2,
    const float* __restrict__ g2w, const float* __restrict__ bn2_1,
    const float* __restrict__ g3w, const float* __restrict__ bn3_1,
    const float* __restrict__ r3w,
    short* __restrict__ wt1b, short* __restrict__ wt2b, short* __restrict__ wt3b,
    short* __restrict__ gw2b, short* __restrict__ gw3b, short* __restrict__ rw3b)
{
    const int i = blockIdx.x * 256 + threadIdx.x;
    if (i < 49152) {
        const int o = i / 384, r = i % 384, dt = r / 128, c = r % 128;
        const float s = bn1_2[o] * rsqrtf(bn1_2[384 + o] + 1e-5f);
        wt1b[i] = f2bf(s * w1t[(o*128 + c)*3 + dt]);
    } else if (i < 98304) {
        const int j = i - 49152;
        const int o = j / 384, r = j % 384, dt = r / 128, c = r % 128;
        const float s = bn2_2[o] * rsqrtf(bn2_2[384 + o] + 1e-5f);
        wt2b[j] = f2bf(s * w2t[(o*128 + c)*3 + dt]);
    } else if (i < 294912) {
        const int j = i - 98304;
        const int o = j / 768, r = j % 768, dt = r / 256, c = r % 256;
        const float s = bn3_2[o] * rsqrtf(bn3_2[768 + o] + 1e-5f);
        wt3b[j] = f2bf(s * w3t[(o*256 + c)*3 + dt]);
    } else if (i < 311296) {
        const int j = i - 294912;
        const int o = j / 128;
        const float s = bn2_1[o] * rsqrtf(bn2_1[384 + o] + 1e-5f);
        gw2b[j] = f2bf(s * g2w[j]);
    } else if (i < 344064) {
        const int j = i - 311296;
        const int o = j / 128;
        const float s = bn3_1[o] * rsqrtf(bn3_1[768 + o] + 1e-5f);
        gw3b[j] = f2bf(s * g3w[j]);
    } else if (i < 376832) {
        const int j = i - 344064;
        rw3b[j] = f2bf(r3w[j]);
    }
}

// LDS layout (block1/block2), 52,320 B -> 3 blocks/CU
#define LDS_SZ   52320
#define FA_OFF   26112
#define X6_OFF   40320
#define XA6_OFF  44176
#define TBL_OFF  50688

// ================================================================ KERNEL 1 (512 thr)
__global__ __launch_bounds__(512) void block1_kernel(
    const float* __restrict__ x,
    const float* __restrict__ gw1, const float* __restrict__ gb1, const float* __restrict__ bn1,
    const float* __restrict__ rw1, const float* __restrict__ rb1,
    const float* __restrict__ bn12, const float* __restrict__ tb1, const short* __restrict__ wt1b,
    const short* __restrict__ gw2b, const float* __restrict__ gb2, const float* __restrict__ bn21,
    const float* __restrict__ adjp,
    short* __restrict__ f1_out, short* __restrict__ h2_out)
{
    __shared__ char smem[LDS_SZ];
    float* s_x6  = (float*)(smem + X6_OFF);
    float* s_xa6 = (float*)(smem + XA6_OFF);
    float* s_cw  = (float*)(smem + TBL_OFF);
    int*   s_ci  = (int*)  (smem + TBL_OFF + 768);
    float* s_cs  = (float*)(smem + TBL_OFF + 1536);

    const int r0 = blockIdx.x * 96;
    const int bstart = (r0 / 6144) * 6144;
    const int bend = bstart + 6144;
    const int tid = threadIdx.x;
    const int l = tid & 63, wid = tid >> 6;
    const int m0w = (wid >> 2) * 48;
    const int n0w = (wid & 3) * 32;
    const int lr = l & 15, lk = l >> 4;

    if (tid < 192) { s_cw[tid] = adjp[600 + tid]; s_ci[tid] = (int)adjp[792 + tid]; }
    else if (tid < 216) s_cs[tid - 192] = adjp[576 + (tid - 192)];
    if (tid < 144) {
        const int gr = r0 - 24 + tid;
        float o0=0,o1=0,o2=0,o3=0,o4=0,o5=0;
        if (gr >= bstart && gr < bend) {
            const float ax = x[gr*3+0], ay = x[gr*3+1], az = x[gr*3+2];
            const float angle = sqrtf(ax*ax + ay*ay + az*az);
            const float inv = 1.f / (angle + 1e-8f);
            const float ux = ax*inv, uy = ay*inv, uz = az*inv;
            const float c = cosf(angle), s = sinf(angle), omc = 1.f - c;
            o0 = c + omc*ux*ux;   o1 = omc*ux*uy - s*uz;
            o2 = omc*uy*ux + s*uz; o3 = c + omc*uy*uy;
            o4 = omc*uz*ux - s*uy; o5 = omc*uz*uy + s*ux;
        }
        float* p = s_x6 + tid*6;
        p[0]=o0; p[1]=o1; p[2]=o2; p[3]=o3; p[4]=o4; p[5]=o5;
    }
    __syncthreads();
    for (int idx = tid; idx < 864; idx += 512) {
        const int hr = idx / 6, c = idx % 6;
        const int k = hr % 24, sl = (hr / 24) * 24;
        float a = 0.f;
        #pragma unroll
        for (int u = 0; u < 8; ++u)
            a = fmaf(s_cw[k*8+u], s_x6[(sl + s_ci[k*8+u])*6 + c], a);
        s_xa6[hr*6 + c] = a;
    }
    __syncthreads();
    {
        const int o = tid & 127, q = tid >> 7;
        const float s1 = bn1[o] * rsqrtf(bn1[384 + o] + 1e-5f);
        const float t1 = bn1[128 + o] - bn1[256 + o] * s1;
        const float g1 = s1 * gb1[o];
        float wg[6];
        #pragma unroll
        for (int c = 0; c < 6; ++c) wg[c] = gw1[o*6 + c];
        for (int hr = q; hr < 144; hr += 4) {
            const int gr = r0 - 24 + hr;
            short hv = 0;
            if (gr >= bstart && gr < bend) {
                float a = 0.f;
                #pragma unroll
                for (int c = 0; c < 6; ++c) a = fmaf(s_xa6[hr*6 + c], wg[c], a);
                hv = f2bf(fmaxf(s1*a + t1 + g1*s_cs[hr % 24], 0.f));
            }
            *(short*)(smem + hr*256 + ((((o*2)&0xF0)) ^ ((hr&7)<<4)) + ((o*2)&14)) = hv;
        }
    }
    __syncthreads();
    f32x4 acc[3][2];
    #pragma unroll
    for (int mi = 0; mi < 3; ++mi)
        #pragma unroll
        for (int ni = 0; ni < 2; ++ni) acc[mi][ni] = (f32x4){0.f,0.f,0.f,0.f};
    #pragma unroll
    for (int dt = 0; dt < 3; ++dt) {
        #pragma unroll
        for (int kc = 0; kc < 4; ++kc) {
            short8v bfr[2], afr[3];
            #pragma unroll
            for (int ni = 0; ni < 2; ++ni) {
                const int n = n0w + ni*16 + lr;
                bfr[ni] = *(const short8v*)(wt1b + (size_t)n*384 + dt*128 + kc*32 + lk*8);
            }
            #pragma unroll
            for (int mi = 0; mi < 3; ++mi) {
                const int row = m0w + dt*24 + mi*16 + lr;
                afr[mi] = *(const short8v*)(smem + row*256 + ((kc*64 + lk*16) ^ ((row&7)<<4)));
            }
            #pragma unroll
            for (int mi = 0; mi < 3; ++mi)
                #pragma unroll
                for (int ni = 0; ni < 2; ++ni)
                    acc[mi][ni] = __builtin_amdgcn_mfma_f32_16x16x32_bf16(afr[mi], bfr[ni], acc[mi][ni], 0, 0, 0);
        }
    }
    __syncthreads();
    #pragma unroll
    for (int ni = 0; ni < 2; ++ni) {
        const int o = n0w + ni*16 + lr;
        const float s2 = bn12[o] * rsqrtf(bn12[384 + o] + 1e-5f);
        const float bias = (bn12[128 + o] - bn12[256 + o]*s2) + s2*tb1[o];
        float wr[6];
        #pragma unroll
        for (int c = 0; c < 6; ++c) wr[c] = rw1[o*6 + c];
        const float rb = rb1[o];
        #pragma unroll
        for (int mi = 0; mi < 3; ++mi)
            #pragma unroll
            for (int rg = 0; rg < 4; ++rg) {
                const int rl = m0w + mi*16 + lk*4 + rg;
                float r = rb;
                #pragma unroll
                for (int c = 0; c < 6; ++c) r = fmaf(s_x6[(rl+24)*6 + c], wr[c], r);
                const short hv = f2bf(fmaxf(acc[mi][ni][rg] + bias + r, 0.f));
                f1_out[(size_t)(r0 + rl)*128 + o] = hv;
                *(short*)(smem + rl*272 + o*2) = hv;
            }
    }
    __syncthreads();
    for (int task = tid; task < 96*16; task += 512) {
        const int row = task >> 4, cg = task & 15;
        const int k = row % 24, sl = (row / 24) * 24;
        float a[8] = {0,0,0,0,0,0,0,0};
        #pragma unroll
        for (int u = 0; u < 8; ++u) {
            const float wgt = s_cw[k*8+u];
            const short8v v = *(const short8v*)(smem + (sl + s_ci[k*8+u])*272 + cg*16);
            #pragma unroll
            for (int e = 0; e < 8; ++e) a[e] = fmaf(wgt, bf2f(v[e]), a[e]);
        }
        short8v o8;
        #pragma unroll
        for (int e = 0; e < 8; ++e) o8[e] = f2bf(a[e]);
        *(short8v*)(smem + FA_OFF + row*256 + ((cg*16) ^ ((row&7)<<4))) = o8;
    }
    __syncthreads();
    #pragma unroll
    for (int mi = 0; mi < 3; ++mi)
        #pragma unroll
        for (int ni = 0; ni < 2; ++ni) acc[mi][ni] = (f32x4){0.f,0.f,0.f,0.f};
    #pragma unroll
    for (int kc = 0; kc < 4; ++kc) {
        short8v bfr[2], afr[3];
        #pragma unroll
        for (int ni = 0; ni < 2; ++ni) {
            const int n = n0w + ni*16 + lr;
            bfr[ni] = *(const short8v*)(gw2b + (size_t)n*128 + kc*32 + lk*8);
        }
        #pragma unroll
        for (int mi = 0; mi < 3; ++mi) {
            const int row = m0w + mi*16 + lr;
            afr[mi] = *(const short8v*)(smem + FA_OFF + row*256 + ((kc*64 + lk*16) ^ ((row&7)<<4)));
        }
        #pragma unroll
        for (int mi = 0; mi < 3; ++mi)
            #pragma unroll
            for (int ni = 0; ni < 2; ++ni)
                acc[mi][ni] = __builtin_amdgcn_mfma_f32_16x16x32_bf16(afr[mi], bfr[ni], acc[mi][ni], 0, 0, 0);
    }
    #pragma unroll
    for (int ni = 0; ni < 2; ++ni) {
        const int o = n0w + ni*16 + lr;
        const float s = bn21[o] * rsqrtf(bn21[384 + o] + 1e-5f);
        const float t = bn21[128 + o] - bn21[256 + o]*s;
        const float g = s * gb2[o];
        #pragma unroll
        for (int mi = 0; mi < 3; ++mi)
            #pragma unroll
            for (int rg = 0; rg < 4; ++rg) {
                const int rl = m0w + mi*16 + lk*4 + rg;
                h2_out[(size_t)(r0 + rl)*128 + o] = f2bf(fmaxf(acc[mi][ni][rg] + t + g*s_cs[rl % 24], 0.f));
            }
    }
}

// ================================================================ KERNEL 2 (512 thr)
__global__ __launch_bounds__(512) void block2_kernel(
    const short* __restrict__ h2, const short* __restrict__ wt2b,
    const float* __restrict__ bn22, const float* __restrict__ tb2,
    const short* __restrict__ f1,
    const short* __restrict__ gw3b, const float* __restrict__ gb3, const float* __restrict__ bn31,
    const float* __restrict__ adjp,
    short* __restrict__ f2_out, short* __restrict__ h3_out)
{
    __shared__ char smem[LDS_SZ];
    float* s_cw  = (float*)(smem + TBL_OFF);
    int*   s_ci  = (int*)  (smem + TBL_OFF + 768);
    float* s_cs  = (float*)(smem + TBL_OFF + 1536);

    const int r0 = blockIdx.x * 96;
    const int bstart = (r0 / 6144) * 6144;
    const int bend = bstart + 6144;
    const int tid = threadIdx.x;
    const int l = tid & 63, wid = tid >> 6;
    const int m0w = (wid >> 2) * 48;
    const int lr = l & 15, lk = l >> 4;

    if (tid < 192) { s_cw[tid] = adjp[600 + tid]; s_ci[tid] = (int)adjp[792 + tid]; }
    else if (tid < 216) s_cs[tid - 192] = adjp[576 + (tid - 192)];
    for (int ch = tid; ch < 144*16; ch += 512) {
        const int row = ch >> 4, cg = ch & 15;
        const int gr = r0 - 24 + row;
        float4 v = make_float4(0.f,0.f,0.f,0.f);
        if (gr >= bstart && gr < bend)
            v = *(const float4*)(h2 + (size_t)gr*128 + cg*8);
        *(float4*)(smem + row*256 + ((cg*16) ^ ((row&7)<<4))) = v;
    }
    __syncthreads();
    {
        const int n0w = (wid & 3) * 32;
        f32x4 acc[3][2];
        #pragma unroll
        for (int mi = 0; mi < 3; ++mi)
            #pragma unroll
            for (int ni = 0; ni < 2; ++ni) acc[mi][ni] = (f32x4){0.f,0.f,0.f,0.f};
        #pragma unroll
        for (int dt = 0; dt < 3; ++dt) {
            #pragma unroll
            for (int kc = 0; kc < 4; ++kc) {
                short8v bfr[2], afr[3];
                #pragma unroll
                for (int ni = 0; ni < 2; ++ni) {
                    const int n = n0w + ni*16 + lr;
                    bfr[ni] = *(const short8v*)(wt2b + (size_t)n*384 + dt*128 + kc*32 + lk*8);
                }
                #pragma unroll
                for (int mi = 0; mi < 3; ++mi) {
                    const int row = m0w + dt*24 + mi*16 + lr;
                    afr[mi] = *(const short8v*)(smem + row*256 + ((kc*64 + lk*16) ^ ((row&7)<<4)));
                }
                #pragma unroll
                for (int mi = 0; mi < 3; ++mi)
                    #pragma unroll
                    for (int ni = 0; ni < 2; ++ni)
                        acc[mi][ni] = __builtin_amdgcn_mfma_f32_16x16x32_bf16(afr[mi], bfr[ni], acc[mi][ni], 0, 0, 0);
            }
        }
        __syncthreads();
        #pragma unroll
        for (int ni = 0; ni < 2; ++ni) {
            const int o = n0w + ni*16 + lr;
            const float s = bn22[o] * rsqrtf(bn22[384 + o] + 1e-5f);
            const float bias = (bn22[128 + o] - bn22[256 + o]*s) + s*tb2[o];
            #pragma unroll
            for (int mi = 0; mi < 3; ++mi)
                #pragma unroll
                for (int rg = 0; rg < 4; ++rg) {
                    const int rl = m0w + mi*16 + lk*4 + rg;
                    const float res = bf2f(f1[(size_t)(r0 + rl)*128 + o]);
                    const short hv = f2bf(fmaxf(acc[mi][ni][rg] + bias + res, 0.f));
                    *(short*)(smem + rl*272 + o*2) = hv;
                    f2_out[(size_t)(r0 + rl)*128 + o] = hv;
                }
        }
    }
    __syncthreads();
    for (int task = tid; task < 96*16; task += 512) {
        const int row = task >> 4, cg = task & 15;
        const int k = row % 24, sl = (row / 24) * 24;
        float a[8] = {0,0,0,0,0,0,0,0};
        #pragma unroll
        for (int u = 0; u < 8; ++u) {
            const float wgt = s_cw[k*8+u];
            const short8v v = *(const short8v*)(smem + (sl + s_ci[k*8+u])*272 + cg*16);
            #pragma unroll
            for (int e = 0; e < 8; ++e) a[e] = fmaf(wgt, bf2f(v[e]), a[e]);
        }
        short8v o8;
        #pragma unroll
        for (int e = 0; e < 8; ++e) o8[e] = f2bf(a[e]);
        *(short8v*)(smem + FA_OFF + row*256 + ((cg*16) ^ ((row&7)<<4))) = o8;
    }
    __syncthreads();
    {
        const int n0w = (wid & 3) * 64;
        f32x4 acc[3][4];
        #pragma unroll
        for (int mi = 0; mi < 3; ++mi)
            #pragma unroll
            for (int ni = 0; ni < 4; ++ni) acc[mi][ni] = (f32x4){0.f,0.f,0.f,0.f};
        #pragma unroll
        for (int kc = 0; kc < 4; ++kc) {
            short8v bfr[4], afr[3];
            #pragma unroll
            for (int ni = 0; ni < 4; ++ni) {
                const int n = n0w + ni*16 + lr;
                bfr[ni] = *(const short8v*)(gw3b + (size_t)n*128 + kc*32 + lk*8);
            }
            #pragma unroll
            for (int mi = 0; mi < 3; ++mi) {
                const int row = m0w + mi*16 + lr;
                afr[mi] = *(const short8v*)(smem + FA_OFF + row*256 + ((kc*64 + lk*16) ^ ((row&7)<<4)));
            }
            #pragma unroll
            for (int mi = 0; mi < 3; ++mi)
                #pragma unroll
                for (int ni = 0; ni < 4; ++ni)
                    acc[mi][ni] = __builtin_amdgcn_mfma_f32_16x16x32_bf16(afr[mi], bfr[ni], acc[mi][ni], 0, 0, 0);
        }
        #pragma unroll
        for (int ni = 0; ni < 4; ++ni) {
            const int o = n0w + ni*16 + lr;
            const float s = bn31[o] * rsqrtf(bn31[768 + o] + 1e-5f);
            const float t = bn31[256 + o] - bn31[512 + o]*s;
            const float g = s * gb3[o];
            #pragma unroll
            for (int mi = 0; mi < 3; ++mi)
                #pragma unroll
                for (int rg = 0; rg < 4; ++rg) {
                    const int rl = m0w + mi*16 + lk*4 + rg;
                    h3_out[(size_t)(r0 + rl)*256 + o] = f2bf(fmaxf(acc[mi][ni][rg] + t + g*s_cs[rl % 24], 0.f));
                }
        }
    }
}

// ================================================================ KERNEL 3 (512 thr, 192-row tiles, full N=256)
// conv3 (K=768) over h3 + R3 (f2 @ rw3, K=128, f2 staged via LDS) + BN + relu + pool.
// XCD-chunked blockIdx swizzle: consecutive tiles share halo rows + weights on one L2.
__global__ __launch_bounds__(512) void conv3_pool_kernel(
    const short* __restrict__ A, const short* __restrict__ Bw,
    const float* __restrict__ bn, const float* __restrict__ tb,
    const short* __restrict__ f2, const short* __restrict__ rw3b, const float* __restrict__ rb3,
    float* __restrict__ pooled)
{
    __shared__ char lds[240 * 256];          // 61,440 B -> 2 blocks/CU
    const int cpx = gridDim.x >> 3;          // gridDim.x % 8 == 0 (32*G)
    const int bid = blockIdx.x;
    const int tile = (bid % 8) * cpx + bid / 8;
    const int r0 = tile * 192;
    const int bb = r0 / 6144;
    const int bstart = bb * 6144, bend = bstart + 6144;
    const int tid = threadIdx.x, l = tid & 63, wid = tid >> 6;
    const int m0w = (wid >> 2) * 96;          // 2-way M (96 rows, 6 frags)
    const int n0w = (wid & 3) * 64;           // 4-way N (64 cols, 4 frags)
    const int lr = l & 15, lk = l >> 4;

    f32x4 acc[6][4];
    #pragma unroll
    for (int mi = 0; mi < 6; ++mi)
        #pragma unroll
        for (int ni = 0; ni < 4; ++ni) acc[mi][ni] = (f32x4){0.f,0.f,0.f,0.f};

    for (int p = 0; p < 2; ++p) {
        if (p) __syncthreads();
        for (int ch = tid; ch < 240 * 16; ch += 512) {
            const int row = ch >> 4, c16 = ch & 15;
            const int gr = r0 - 24 + row;
            float4 v = make_float4(0.f,0.f,0.f,0.f);
            if (gr >= bstart && gr < bend)
                v = *(const float4*)(A + (size_t)gr * 256 + p * 128 + c16 * 8);
            *(float4*)(lds + row * 256 + ((c16 * 16) ^ ((row & 7) << 4))) = v;
        }
        __syncthreads();
        #pragma unroll
        for (int dt = 0; dt < 3; ++dt) {
            #pragma unroll
            for (int kc = 0; kc < 4; ++kc) {
                short8v bfr[4], afr[6];
                #pragma unroll
                for (int ni = 0; ni < 4; ++ni) {
                    const int n = n0w + ni * 16 + lr;
                    bfr[ni] = *(const short8v*)(Bw + (size_t)n * 768 + dt * 256 + p * 128 + kc * 32 + lk * 8);
                }
                #pragma unroll
                for (int mi = 0; mi < 6; ++mi) {
                    const int row = m0w + dt * 24 + mi * 16 + lr;
                    afr[mi] = *(const short8v*)(lds + row * 256 + ((kc * 64 + lk * 16) ^ ((row & 7) << 4)));
                }
                #pragma unroll
                for (int mi = 0; mi < 6; ++mi)
                    #pragma unroll
                    for (int ni = 0; ni < 4; ++ni)
                        acc[mi][ni] = __builtin_amdgcn_mfma_f32_16x16x32_bf16(afr[mi], bfr[ni], acc[mi][ni], 0, 0, 0);
            }
        }
    }
    // stage f2 tile (192 x 128ch) into LDS, R3 MFMA from LDS
    __syncthreads();
    for (int ch = tid; ch < 192 * 16; ch += 512) {
        const int row = ch >> 4, c16 = ch & 15;
        const float4 v = *(const float4*)(f2 + (size_t)(r0 + row) * 128 + c16 * 8);
        *(float4*)(lds + row * 256 + ((c16 * 16) ^ ((row & 7) << 4))) = v;
    }
    __syncthreads();
    #pragma unroll
    for (int kc = 0; kc < 4; ++kc) {
        short8v bfr[4], afr[6];
        #pragma unroll
        for (int ni = 0; ni < 4; ++ni) {
            const int n = n0w + ni * 16 + lr;
            bfr[ni] = *(const short8v*)(rw3b + (size_t)n * 128 + kc * 32 + lk * 8);
        }
        #pragma unroll
        for (int mi = 0; mi < 6; ++mi) {
            const int row = m0w + mi * 16 + lr;
            afr[mi] = *(const short8v*)(lds + row * 256 + ((kc * 64 + lk * 16) ^ ((row & 7) << 4)));
        }
        #pragma unroll
        for (int mi = 0; mi < 6; ++mi)
            #pragma unroll
            for (int ni = 0; ni < 4; ++ni)
                acc[mi][ni] = __builtin_amdgcn_mfma_f32_16x16x32_bf16(afr[mi], bfr[ni], acc[mi][ni], 0, 0, 0);
    }

    float psum[4] = {0.f, 0.f, 0.f, 0.f};
    #pragma unroll
    for (int ni = 0; ni < 4; ++ni) {
        const int o = n0w + ni * 16 + lr;
        const float s = bn[o] * rsqrtf(bn[768 + o] + 1e-5f);
        const float t = bn[256 + o] - bn[512 + o] * s;
        const float bias = s * tb[o] + t + rb3[o];
        #pragma unroll
        for (int mi = 0; mi < 6; ++mi)
            #pragma unroll
            for (int rg = 0; rg < 4; ++rg)
                psum[ni] += fmaxf(acc[mi][ni][rg] + bias, 0.f);
    }
    #pragma unroll
    for (int ni = 0; ni < 4; ++ni) {
        float v = psum[ni];
        v += __shfl_xor(v, 16);
        v += __shfl_xor(v, 32);
        if (l < 16) atomicAdd(pooled + (size_t)bb * 256 + (n0w + ni * 16 + l), v);
    }
}

// ---------------------------------------------------------------- head
__global__ __launch_bounds__(256) void head_kernel(const float* __restrict__ pooled_sums,
    const float* __restrict__ ow, const float* __restrict__ ob, float* __restrict__ outp) {
    __shared__ float pooled[256];
    const int b = blockIdx.x, tid = threadIdx.x;
    pooled[tid] = pooled_sums[(size_t)b*256 + tid] * (1.f/6144.f);
    __syncthreads();
    for (int rep = 0; rep < 2; ++rep) {
        const int oo = rep*256 + tid;
        float a = ob[oo];
        const float4* wr = (const float4*)(ow + (size_t)oo*256);
        for (int c4 = 0; c4 < 64; ++c4) {
            const float4 w = wr[c4];
            const float4 p = *(const float4*)&pooled[c4*4];
            a += w.x*p.x + w.y*p.y + w.z*p.z + w.w*p.w;
        }
        outp[(size_t)b*512 + oo] = a;
    }
}

// ---------------------------------------------------------------- launch
extern "C" void kernel_launch(void* const* d_in, const int* in_sizes, int n_in,
                              void* d_out, int out_size, void* d_ws, size_t ws_size,
                              hipStream_t stream)
{
    const float* x        = (const float*)d_in[0];
    const float* b1_gcn_w = (const float*)d_in[1];
    const float* b1_gcn_b = (const float*)d_in[2];
    const float* b1_bn1   = (const float*)d_in[3];
    const float* b1_tcn_w = (const float*)d_in[4];
    const float* b1_tcn_b = (const float*)d_in[5];
    const float* b1_bn2   = (const float*)d_in[6];
    const float* b1_res_w = (const float*)d_in[7];
    const float* b1_res_b = (const float*)d_in[8];
    const float* b2_gcn_w = (const float*)d_in[9];
    const float* b2_gcn_b = (const float*)d_in[10];
    const float* b2_bn1   = (const float*)d_in[11];
    const float* b2_tcn_w = (const float*)d_in[12];
    const float* b2_tcn_b = (const float*)d_in[13];
    const float* b2_bn2   = (const float*)d_in[14];
    const float* b3_gcn_w = (const float*)d_in[15];
    const float* b3_gcn_b = (const float*)d_in[16];
    const float* b3_bn1   = (const float*)d_in[17];
    const float* b3_tcn_w = (const float*)d_in[18];
    const float* b3_tcn_b = (const float*)d_in[19];
    const float* b3_bn2   = (const float*)d_in[20];
    const float* b3_res_w = (const float*)d_in[21];
    const float* b3_res_b = (const float*)d_in[22];
    const float* out_w    = (const float*)d_in[23];
    const float* out_b    = (const float*)d_in[24];

    // ---- fixed workspace carve
    char* w = (char*)d_ws;
    float* adjp = (float*)w;   w += 4096;
    short* wt1b = (short*)w;   w += 98304;
    short* wt2b = (short*)w;   w += 98304;
    short* wt3b = (short*)w;   w += 393216;
    short* gw2b = (short*)w;   w += 32768;
    short* gw3b = (short*)w;   w += 65536;
    short* rw3b = (short*)w;   w += 65536;
    float* pooled = (float*)w; w += 32768;
    const size_t fixed = (size_t)(w - (char*)d_ws);

    // ---- adaptive batch-group: per-G bytes = 6144 * (256+256+512) = 6,291,456
    //      (f2 aliases f1: block2 reads f1[row] then writes f2[row] in the same thread)
    int G = 1;
    {
        const int tiers[6] = {32, 16, 8, 4, 2, 1};
        for (int ti = 0; ti < 6; ++ti) {
            const size_t need = fixed + (size_t)tiers[ti] * 6291456ull;
            if (need <= ws_size) { G = tiers[ti]; break; }
        }
    }
    const size_t MG = (size_t)G * 6144;

    short* f1 = (short*)w;           // MG*128  (also serves as f2 after block2)
    short* h2 = f1 + MG*128;         // MG*128
    short* h3 = h2 + MG*128;         // MG*256
    short* f2 = f1;                  // alias

    hipMemsetAsync(pooled, 0, 32*256*sizeof(float), stream);
    adj_init_kernel<<<1, 256, 0, stream>>>(adjp);
    prep_kernel<<<1472, 256, 0, stream>>>(b1_tcn_w, b1_bn2, b2_tcn_w, b2_bn2, b3_tcn_w, b3_bn2,
                                          b2_gcn_w, b2_bn1, b3_gcn_w, b3_bn1, b3_res_w,
                                          wt1b, wt2b, wt3b, gw2b, gw3b, rw3b);

    for (int b0 = 0; b0 < B_; b0 += G) {
        block1_kernel<<<64*G, 512, 0, stream>>>(
            x + (size_t)b0*6144*3,
            b1_gcn_w, b1_gcn_b, b1_bn1, b1_res_w, b1_res_b,
            b1_bn2, b1_tcn_b, wt1b,
            gw2b, b2_gcn_b, b2_bn1, adjp, f1, h2);
        block2_kernel<<<64*G, 512, 0, stream>>>(
            h2, wt2b, b2_bn2, b2_tcn_b, f1,
            gw3b, b3_gcn_b, b3_bn1, adjp, f2, h3);
        conv3_pool_kernel<<<32*G, 512, 0, stream>>>(
            h3, wt3b, b3_bn2, b3_tcn_b, f2, rw3b, b3_res_b, pooled + (size_t)b0*256);
    }

    head_kernel<<<B_, 256, 0, stream>>>(pooled, out_w, out_b, (float*)d_out);
}